// Round 1
// baseline (10997.768 us; speedup 1.0000x reference)
//
#include <hip/hip_runtime.h>
#include <math.h>

#define SIDES 2
#define LAYERS 2
#define NTREE 8
#define NPT 1093
#define NN (NTREE*NPT)        // 8744
#define EE 256
#define HH 512
#define NUSERS 2000
#define NPOI 5000
#define NCAT 300
#define NCOO 50
#define FUSEN 5350
#define TMAXN 600
#define TOKMAX 5832           // 8*729
#define PARMAX 1944           // 8*243

// side strides (floats)
constexpr long X_S   = (long)NN*EE;
constexpr long H_S   = (long)NN*HH;
constexpr long Z_S   = (long)TOKMAX*HH;
constexpr long QKV_S = (long)TOKMAX*3*HH;
constexpr long XL_S  = (long)TOKMAX*EE;
constexpr long WX_S  = (long)PARMAX*HH;

constexpr long OUT_S   = 46780400L;   // per-side output block
constexpr long CAT_OFF = 43720000L;
constexpr long COO_OFF = 46343200L;

__device__ __forceinline__ float sigm(float x){ return 1.f/(1.f+expf(-x)); }

// ---------------- embedding ----------------
__global__ void embed_k(const int* __restrict__ uid, const int* __restrict__ fid,
                        const int* __restrict__ tid, const int* __restrict__ mask,
                        const float* __restrict__ uemb, const float* __restrict__ femb,
                        const float* __restrict__ tpe, float* __restrict__ X){
  int s = blockIdx.z; long i = blockIdx.x; int d = threadIdx.x;
  int m = mask[(long)s*NN + i];
  int u = uid[(long)s*NN + i]*m, f = fid[(long)s*NN + i]*m, t = tid[(long)s*NN + i]*m;
  float e = (d < 128) ? uemb[((long)s*NUSERS + u)*128 + d]
                      : femb[((long)s*FUSEN + f)*128 + (d-128)];
  e += 0.5f * tpe[((long)s*TMAXN + t)*256 + d];
  X[(long)s*X_S + i*EE + d] = e * (float)m;
}

// ---------------- row gather (tree-strided -> dense) ----------------
__global__ void gather_rows_k(float* __restrict__ dst, const float* __restrict__ src,
                              int rows_per_tree, int src_off, int cols,
                              long sDst, long sSrc){
  int s = blockIdx.z; int r = blockIdx.x;
  int tree = r / rows_per_tree, w = r - tree*rows_per_tree;
  const float* sp = src + (long)s*sSrc + (long)(tree*NPT + src_off + w)*cols;
  float* dp = dst + (long)s*sDst + (long)r*cols;
  for (int d = threadIdx.x; d < cols; d += blockDim.x) dp[d] = sp[d];
}

// ---------------- generic f32 GEMM: C = epilogue(A @ W^T + bias) ----------------
// MODE 0: C = acc+bias; 1: relu; 2: C += acc(+bias); 3: C = a0*(acc+bias)+sum(mtl);
// 4: C += a_idx*(acc+bias)
template<int MODE>
__global__ void __launch_bounds__(256)
gemm_k(const float* __restrict__ A, const float* __restrict__ W,
       const float* __restrict__ bias, float* __restrict__ C,
       int M, int Nc, int K,
       long sA, long sW, long sB, long sC,
       const float* __restrict__ mtl, int mtlIdx){
  int s = blockIdx.z;
  A += (long)s*sA; W += (long)s*sW; C += (long)s*sC;
  if (bias) bias += (long)s*sB;
  __shared__ float As[16][65];
  __shared__ float Ws[16][65];
  int tid = threadIdx.x;
  int tx = tid & 15, ty = tid >> 4;
  int m0 = blockIdx.y*64, n0 = blockIdx.x*64;
  float acc[4][4] = {};
  for (int k0 = 0; k0 < K; k0 += 16){
    #pragma unroll
    for (int i = 0; i < 4; i++){
      int idx = tid + i*256;
      int mm = idx >> 4, kk = idx & 15;
      int gm = m0 + mm, gk = k0 + kk;
      As[kk][mm] = (gm < M  && gk < K) ? A[(long)gm*K + gk] : 0.f;
      int gn = n0 + mm;
      Ws[kk][mm] = (gn < Nc && gk < K) ? W[(long)gn*K + gk] : 0.f;
    }
    __syncthreads();
    #pragma unroll
    for (int kk = 0; kk < 16; kk++){
      float a[4], b[4];
      #pragma unroll
      for (int i = 0; i < 4; i++) a[i] = As[kk][ty + i*16];
      #pragma unroll
      for (int j = 0; j < 4; j++) b[j] = Ws[kk][tx + j*16];
      #pragma unroll
      for (int i = 0; i < 4; i++)
        #pragma unroll
        for (int j = 0; j < 4; j++)
          acc[i][j] += a[i]*b[j];
    }
    __syncthreads();
  }
  float alpha = 1.f, cst = 0.f;
  if (MODE == 3 || MODE == 4){
    const float* mt = mtl + (long)s*3;
    alpha = 0.5f*expf(-mt[mtlIdx]);
    if (MODE == 3) cst = mt[0] + mt[1] + mt[2];
  }
  #pragma unroll
  for (int i = 0; i < 4; i++){
    int gm = m0 + ty + i*16; if (gm >= M) continue;
    #pragma unroll
    for (int j = 0; j < 4; j++){
      int gn = n0 + tx + j*16; if (gn >= Nc) continue;
      float v = acc[i][j] + (bias ? bias[gn] : 0.f);
      long off = (long)gm*Nc + gn;
      if      (MODE == 0) C[off] = v;
      else if (MODE == 1) C[off] = fmaxf(v, 0.f);
      else if (MODE == 2) C[off] += v;
      else if (MODE == 3) C[off] = alpha*v + cst;
      else                C[off] += alpha*v;
    }
  }
}

// ---------------- 3x3 attention, NH=2 heads of 256 ----------------
__global__ void attn_k(const float* __restrict__ qkv, float* __restrict__ o){
  int s = blockIdx.z, m = blockIdx.x, h = blockIdx.y;
  const float* base = qkv + (long)s*QKV_S + (long)m*3*1536 + (long)h*256;
  int t = threadIdx.x;
  float q[3], k[3], v[3];
  #pragma unroll
  for (int i = 0; i < 3; i++){
    q[i] = base[(long)i*1536 + t];
    k[i] = base[(long)i*1536 + 512 + t];
    v[i] = base[(long)i*1536 + 1024 + t];
  }
  __shared__ float sm[4];
  __shared__ float att[9];
  #pragma unroll
  for (int i = 0; i < 3; i++)
    #pragma unroll
    for (int j = 0; j < 3; j++){
      float p = q[i]*k[j];
      for (int off = 32; off; off >>= 1) p += __shfl_down(p, off);
      __syncthreads();
      if ((t & 63) == 0) sm[t >> 6] = p;
      __syncthreads();
      if (t == 0) att[i*3 + j] = (sm[0]+sm[1]+sm[2]+sm[3]) * 0.0625f; // 256^-0.5
    }
  __syncthreads();
  if (t < 3){
    float a = att[t*3], b = att[t*3+1], c = att[t*3+2];
    float mx = fmaxf(a, fmaxf(b, c));
    a = expf(a-mx); b = expf(b-mx); c = expf(c-mx);
    float inv = 1.f/(a+b+c);
    att[t*3] = a*inv; att[t*3+1] = b*inv; att[t*3+2] = c*inv;
  }
  __syncthreads();
  float* ob = o + (long)s*Z_S + (long)m*3*512 + (long)h*256;
  #pragma unroll
  for (int i = 0; i < 3; i++)
    ob[(long)i*512 + t] = att[i*3]*v[0] + att[i*3+1]*v[1] + att[i*3+2]*v[2];
}

// ---------------- z = LN(z + t) over 512 ----------------
__global__ void add_ln_k(float* __restrict__ z, const float* __restrict__ tbuf,
                         const float* __restrict__ w, const float* __restrict__ b,
                         long zs, long ts, long wstr){
  int s = blockIdx.z; long r = blockIdx.x;
  float* zr = z + (long)s*zs + r*HH;
  const float* tr = tbuf + (long)s*ts + r*HH;
  const float* wr = w + (long)s*wstr;
  const float* br = b + (long)s*wstr;
  int d0 = threadIdx.x, d1 = threadIdx.x + 256;
  float x0 = zr[d0] + tr[d0], x1 = zr[d1] + tr[d1];
  __shared__ float sm[4];
  float tsum = x0 + x1;
  for (int off = 32; off; off >>= 1) tsum += __shfl_down(tsum, off);
  if ((threadIdx.x & 63) == 0) sm[threadIdx.x >> 6] = tsum;
  __syncthreads();
  float mean = (sm[0]+sm[1]+sm[2]+sm[3]) * (1.f/512.f);
  float e0 = x0 - mean, e1 = x1 - mean;
  float vs = e0*e0 + e1*e1;
  __syncthreads();
  for (int off = 32; off; off >>= 1) vs += __shfl_down(vs, off);
  if ((threadIdx.x & 63) == 0) sm[threadIdx.x >> 6] = vs;
  __syncthreads();
  float var = (sm[0]+sm[1]+sm[2]+sm[3]) * (1.f/512.f);
  float inv = 1.f/sqrtf(var + 1e-5f);
  zr[d0] = e0*inv*wr[d0] + br[d0];
  zr[d1] = e1*inv*wr[d1] + br[d1];
}

// ---------------- leaf LSTM cell ----------------
__global__ void leaf_k(const float* __restrict__ iou, const float* __restrict__ c0,
                       float* hbuf, float* cbuf){
  int s = blockIdx.z, p = blockIdx.x;
  int tree = p / 729, j = p - tree*729;
  long row = (long)(tree*NPT + 364 + j)*512;
  const float* iour = iou + (long)s*QKV_S + (long)p*1536;
  const float* c0r = c0 + (long)s*H_S + row;
  for (int d = threadIdx.x; d < 512; d += 256){
    float cn = sigm(iour[d]) * tanhf(iour[1024 + d]) + c0r[d];
    float hn = sigm(iour[512 + d]) * tanhf(cn);
    hbuf[(long)s*H_S + row + d] = hn;
    cbuf[(long)s*H_S + row + d] = cn;
  }
}

// ---------------- internal-node combine ----------------
__global__ void combine_k(const float* __restrict__ iou, const float* __restrict__ hc,
                          const float* __restrict__ wx, const float* __restrict__ bfv,
                          const float* cbuf, float* hbuf, float* cout,
                          int n, int st, int cs){
  int s = blockIdx.z, p = blockIdx.x;
  int tree = p / n, j = p - tree*n;
  const float* iour = iou + (long)s*QKV_S + (long)p*1536;
  const float* hcr  = hc  + (long)s*Z_S  + (long)p*1536;
  const float* wxr  = wx  + (long)s*WX_S + (long)p*512;
  const float* bfr  = bfv + (long)s*512;
  const float* cch  = cbuf + (long)s*H_S + (long)(tree*NPT + cs + 3*j)*512;
  long orow = (long)s*H_S + (long)(tree*NPT + st + j)*512;
  for (int d = threadIdx.x; d < 512; d += 256){
    float wv = wxr[d] + bfr[d];
    float cpre = 0.f;
    #pragma unroll
    for (int ch = 0; ch < 3; ch++){
      float fg = sigm(wv + hcr[ch*512 + d]);
      cpre += fg * cch[ch*512 + d];
    }
    float iv = iour[d], ov = iour[512 + d], uv = iour[1024 + d];
    float cn = sigm(iv)*tanhf(uv) + cpre;
    float hn = sigm(ov)*tanhf(cn);
    hbuf[orow + d] = hn;
    cout[orow + d] = cn;
  }
}

#define GEMM(MODE, A, W, BI, CC, M, Nc, K, sA, sW, sB, sC, MTL, IDX)                    \
  gemm_k<MODE><<<dim3(((Nc)+63)/64, ((M)+63)/64, SIDES), 256, 0, stream>>>(             \
      A, W, BI, CC, M, Nc, K, sA, sW, sB, sC, MTL, IDX)

extern "C" void kernel_launch(void* const* d_in, const int* in_sizes, int n_in,
                              void* d_out, int out_size, void* d_ws, size_t ws_size,
                              hipStream_t stream){
  (void)in_sizes; (void)n_in; (void)out_size;
  const int*   user_ids  = (const int*)d_in[0];
  const int*   feat_ids  = (const int*)d_in[1];
  const int*   time_ids  = (const int*)d_in[2];
  const int*   mask      = (const int*)d_in[3];
  const float* user_emb  = (const float*)d_in[6];
  const float* fuse_emb  = (const float*)d_in[7];
  const float* time_pe   = (const float*)d_in[8];
  const float* Wf        = (const float*)d_in[9];
  const float* bf        = (const float*)d_in[10];
  const float* Wiou      = (const float*)d_in[11];
  const float* Uiou      = (const float*)d_in[12];
  const float* biou      = (const float*)d_in[13];
  const float* attn_in_w = (const float*)d_in[14];
  const float* attn_in_b = (const float*)d_in[15];
  const float* attn_out_w= (const float*)d_in[16];
  const float* attn_out_b= (const float*)d_in[17];
  const float* ff1_w     = (const float*)d_in[18];
  const float* ff1_b     = (const float*)d_in[19];
  const float* ff2_w     = (const float*)d_in[20];
  const float* ff2_b     = (const float*)d_in[21];
  const float* ln1_w     = (const float*)d_in[22];
  const float* ln1_b     = (const float*)d_in[23];
  const float* ln2_w     = (const float*)d_in[24];
  const float* ln2_b     = (const float*)d_in[25];
  const float* dec_poi_w = (const float*)d_in[26];
  const float* dec_poi_b = (const float*)d_in[27];
  const float* dec_cat_w = (const float*)d_in[28];
  const float* dec_cat_b = (const float*)d_in[29];
  const float* dec_coo_w = (const float*)d_in[30];
  const float* dec_coo_b = (const float*)d_in[31];
  const float* cat2poi_w = (const float*)d_in[32];
  const float* cat2poi_b = (const float*)d_in[33];
  const float* coo2poi_w = (const float*)d_in[34];
  const float* coo2poi_b = (const float*)d_in[35];
  const float* mtl       = (const float*)d_in[36];
  const float* c0        = (const float*)d_in[37];

  float* out = (float*)d_out;
  float* ws  = (float*)d_ws;

  // H and C always live in ws (71.6 MB). Remaining scratch: ws if big enough,
  // else the side-0 poi region of d_out (written only at the very end).
  float* Hb = ws;
  float* Cb = ws + 2*H_S;
  float *QKV, *Zb, *TMP, *Xb, *XLb, *WXb;
  size_t need = (size_t)(2*(2*H_S + 2*Z_S + QKV_S + X_S + XL_S + WX_S))*4;
  if (ws_size >= need){
    float* p = ws + 4*H_S;
    QKV = p; p += 2*QKV_S;
    Zb  = p; p += 2*Z_S;
    TMP = p; p += 2*Z_S;
    Xb  = p; p += 2*X_S;
    XLb = p; p += 2*XL_S;
    WXb = p;
  } else {
    QKV = out + 0L;
    Zb  = out + 17915904L;
    TMP = out + 23887872L;
    Xb  = out + 29859840L;
    XLb = out + 34336768L;
    WXb = out + 37322752L;
  }

  // 1) embeddings -> X
  embed_k<<<dim3(NN,1,SIDES), 256, 0, stream>>>(user_ids, feat_ids, time_ids, mask,
                                                user_emb, fuse_emb, time_pe, Xb);

  // 2) leaves: gather x rows, iou0 = x@Wiou^T (no bias), LSTM cell
  gather_rows_k<<<dim3(NTREE*729,1,SIDES), 256, 0, stream>>>(XLb, Xb, 729, 364, EE, XL_S, X_S);
  GEMM(0, XLb, Wiou, (const float*)nullptr, QKV, 5832, 1536, 256,
       XL_S, (long)1536*256, 0L, QKV_S, (const float*)nullptr, 0);
  leaf_k<<<dim3(5832,1,SIDES), 256, 0, stream>>>(QKV, c0, Hb, Cb);

  const int p3[7]   = {1,3,9,27,81,243,729};
  const int offs[7] = {0,1,4,13,40,121,364};

  // 3) internal levels, bottom-up
  for (int l = 5; l >= 0; l--){
    int n = p3[l], st = offs[l], cs = offs[l+1];
    int P = NTREE*n, T = 3*P;
    gather_rows_k<<<dim3(T,1,SIDES), 256, 0, stream>>>(Zb, Hb, 3*n, cs, HH, Z_S, H_S);
    for (int L = 0; L < LAYERS; L++){
      GEMM(0, Zb, attn_in_w + (long)L*1536*512, attn_in_b + (long)L*1536, QKV,
           T, 1536, 512, Z_S, (long)LAYERS*1536*512, (long)LAYERS*1536, QKV_S,
           (const float*)nullptr, 0);
      attn_k<<<dim3(P,2,SIDES), 256, 0, stream>>>(QKV, TMP);
      GEMM(0, TMP, attn_out_w + (long)L*512*512, attn_out_b + (long)L*512, QKV,
           T, 512, 512, Z_S, (long)LAYERS*512*512, (long)LAYERS*512, QKV_S,
           (const float*)nullptr, 0);
      add_ln_k<<<dim3(T,1,SIDES), 256, 0, stream>>>(Zb, QKV,
           ln1_w + (long)L*512, ln1_b + (long)L*512, Z_S, QKV_S, (long)LAYERS*512);
      GEMM(1, Zb, ff1_w + (long)L*512*512, ff1_b + (long)L*512, TMP,
           T, 512, 512, Z_S, (long)LAYERS*512*512, (long)LAYERS*512, Z_S,
           (const float*)nullptr, 0);
      GEMM(0, TMP, ff2_w + (long)L*512*512, ff2_b + (long)L*512, QKV,
           T, 512, 512, Z_S, (long)LAYERS*512*512, (long)LAYERS*512, QKV_S,
           (const float*)nullptr, 0);
      add_ln_k<<<dim3(T,1,SIDES), 256, 0, stream>>>(Zb, QKV,
           ln2_w + (long)L*512, ln2_b + (long)L*512, Z_S, QKV_S, (long)LAYERS*512);
    }
    gather_rows_k<<<dim3(P,1,SIDES), 256, 0, stream>>>(XLb, Xb, n, st, EE, XL_S, X_S);
    GEMM(0, XLb, Wf, (const float*)nullptr, WXb, P, 512, 256,
         XL_S, (long)512*256, 0L, WX_S, (const float*)nullptr, 0);
    GEMM(0, XLb, Wiou, biou, QKV, P, 1536, 256,
         XL_S, (long)1536*256, 1536L, QKV_S, (const float*)nullptr, 0);
    GEMM(2, Zb, Uiou, (const float*)nullptr, QKV, P, 1536, 1536,
         Z_S, (long)1536*1536, 0L, QKV_S, (const float*)nullptr, 0);
    combine_k<<<dim3(P,1,SIDES), 256, 0, stream>>>(QKV, Zb, WXb, bf, Cb, Hb, Cb, n, st, cs);
  }

  // 4) decoders
  GEMM(0, Hb, dec_cat_w, dec_cat_b, out + CAT_OFF, NN, NCAT, HH,
       H_S, (long)NCAT*HH, (long)NCAT, OUT_S, (const float*)nullptr, 0);
  GEMM(0, Hb, dec_coo_w, dec_coo_b, out + COO_OFF, NN, NCOO, HH,
       H_S, (long)NCOO*HH, (long)NCOO, OUT_S, (const float*)nullptr, 0);
  GEMM(3, Hb, dec_poi_w, dec_poi_b, out, NN, NPOI, HH,
       H_S, (long)NPOI*HH, (long)NPOI, OUT_S, mtl, 0);
  GEMM(4, out + CAT_OFF, cat2poi_w, cat2poi_b, out, NN, NPOI, NCAT,
       OUT_S, (long)NPOI*NCAT, (long)NPOI, OUT_S, mtl, 1);
  GEMM(4, out + COO_OFF, coo2poi_w, coo2poi_b, out, NN, NPOI, NCOO,
       OUT_S, (long)NPOI*NCOO, (long)NPOI, OUT_S, mtl, 2);
}

// Round 2
// 5113.768 us; speedup vs baseline: 2.1506x; 2.1506x over previous
//
#include <hip/hip_runtime.h>
#include <math.h>

#define SIDES 2
#define LAYERS 2
#define NTREE 8
#define NPT 1093
#define NN (NTREE*NPT)        // 8744
#define EE 256
#define HH 512
#define NUSERS 2000
#define NPOI 5000
#define NCAT 300
#define NCOO 50
#define FUSEN 5350
#define TMAXN 600
#define TOKMAX 5832           // 8*729
#define PARMAX 1944           // 8*243

// side strides (floats)
constexpr long X_S   = (long)NN*EE;
constexpr long H_S   = (long)NN*HH;
constexpr long Z_S   = (long)TOKMAX*HH;
constexpr long QKV_S = (long)TOKMAX*3*HH;
constexpr long XL_S  = (long)TOKMAX*EE;
constexpr long WX_S  = (long)PARMAX*HH;

constexpr long OUT_S   = 46780400L;   // per-side output block
constexpr long CAT_OFF = 43720000L;
constexpr long COO_OFF = 46343200L;

typedef __attribute__((ext_vector_type(8))) short  bf16x8;
typedef __attribute__((ext_vector_type(8))) ushort u16x8;
typedef __attribute__((ext_vector_type(4))) float  f32x4;

__device__ __forceinline__ float sigm(float x){ return 1.f/(1.f+expf(-x)); }

__device__ __forceinline__ ushort f2b(float f){
  union { float f; unsigned u; } v; v.f = f;
  unsigned r = (v.u + 0x7fffu + ((v.u >> 16) & 1u)) >> 16;
  return (ushort)r;
}

// ---------------- embedding ----------------
__global__ void embed_k(const int* __restrict__ uid, const int* __restrict__ fid,
                        const int* __restrict__ tid, const int* __restrict__ mask,
                        const float* __restrict__ uemb, const float* __restrict__ femb,
                        const float* __restrict__ tpe, float* __restrict__ X){
  int s = blockIdx.z; long i = blockIdx.x; int d = threadIdx.x;
  int m = mask[(long)s*NN + i];
  int u = uid[(long)s*NN + i]*m, f = fid[(long)s*NN + i]*m, t = tid[(long)s*NN + i]*m;
  float e = (d < 128) ? uemb[((long)s*NUSERS + u)*128 + d]
                      : femb[((long)s*FUSEN + f)*128 + (d-128)];
  e += 0.5f * tpe[((long)s*TMAXN + t)*256 + d];
  X[(long)s*X_S + i*EE + d] = e * (float)m;
}

// ---------------- row gather (tree-strided -> dense) ----------------
__global__ void gather_rows_k(float* __restrict__ dst, const float* __restrict__ src,
                              int rows_per_tree, int src_off, int cols,
                              long sDst, long sSrc){
  int s = blockIdx.z; int r = blockIdx.x;
  int tree = r / rows_per_tree, w = r - tree*rows_per_tree;
  const float* sp = src + (long)s*sSrc + (long)(tree*NPT + src_off + w)*cols;
  float* dp = dst + (long)s*sDst + (long)r*cols;
  for (int d = threadIdx.x; d < cols; d += blockDim.x) dp[d] = sp[d];
}

// ---------------- bf16 MFMA GEMM: C = epilogue(A @ W^T + bias) ----------------
// A: [M][K] f32, W: [Nc][K] f32 (converted to bf16 during staging).
// MODE 0: C = acc+bias; 1: relu; 2: C += acc(+bias); 3: C = a0*(acc+bias)+sum(mtl);
// 4: C += a_idx*(acc+bias)
template<int MODE>
__global__ void __launch_bounds__(256)
mgemm_k(const float* __restrict__ A, const float* __restrict__ W,
        const float* __restrict__ bias, float* __restrict__ C,
        int M, int Nc, int K,
        long sA, long sW, long sB, long sC,
        const float* __restrict__ mtl, int mtlIdx){
  int s = blockIdx.z;
  A += (long)s*sA; W += (long)s*sW; C += (long)s*sC;
  if (bias) bias += (long)s*sB;
  __shared__ ushort As[128][40];   // stride 40 elems (80B): 16B-aligned, spread banks
  __shared__ ushort Ws[128][40];
  int tid = threadIdx.x;
  int lane = tid & 63, wave = tid >> 6;
  int wr = wave >> 1, wc = wave & 1;           // 2x2 waves of 64x64
  int m0 = blockIdx.y*128, n0 = blockIdx.x*128;
  int srow = tid >> 1, shalf = tid & 1;        // staging: row, k-half (16 elems)
  bool al16 = ((K & 3) == 0);
  f32x4 acc[4][4];
  #pragma unroll
  for (int i = 0; i < 4; i++)
    #pragma unroll
    for (int j = 0; j < 4; j++) acc[i][j] = (f32x4){0.f,0.f,0.f,0.f};

  int fr = lane & 15, kc = lane >> 4;

  for (int k0 = 0; k0 < K; k0 += 32){
    int kb = k0 + shalf*16;
    // stage A rows
    {
      int gm = m0 + srow;
      ushort u[16];
      if (gm < M){
        const float* ap = A + (long)gm*K + kb;
        #pragma unroll
        for (int q = 0; q < 4; q++){
          int gk = kb + q*4;
          if (al16 && gk + 3 < K){
            f32x4 t = *(const f32x4*)(ap + q*4);
            u[q*4+0]=f2b(t[0]); u[q*4+1]=f2b(t[1]); u[q*4+2]=f2b(t[2]); u[q*4+3]=f2b(t[3]);
          } else {
            #pragma unroll
            for (int e = 0; e < 4; e++)
              u[q*4+e] = (gk+e < K) ? f2b(ap[q*4+e]) : (ushort)0;
          }
        }
      } else {
        #pragma unroll
        for (int q = 0; q < 16; q++) u[q] = 0;
      }
      u16x8* dst = (u16x8*)&As[srow][shalf*16];
      dst[0] = (u16x8){u[0],u[1],u[2],u[3],u[4],u[5],u[6],u[7]};
      dst[1] = (u16x8){u[8],u[9],u[10],u[11],u[12],u[13],u[14],u[15]};
    }
    // stage W rows
    {
      int gn = n0 + srow;
      ushort u[16];
      if (gn < Nc){
        const float* wp = W + (long)gn*K + kb;
        #pragma unroll
        for (int q = 0; q < 4; q++){
          int gk = kb + q*4;
          if (al16 && gk + 3 < K){
            f32x4 t = *(const f32x4*)(wp + q*4);
            u[q*4+0]=f2b(t[0]); u[q*4+1]=f2b(t[1]); u[q*4+2]=f2b(t[2]); u[q*4+3]=f2b(t[3]);
          } else {
            #pragma unroll
            for (int e = 0; e < 4; e++)
              u[q*4+e] = (gk+e < K) ? f2b(wp[q*4+e]) : (ushort)0;
          }
        }
      } else {
        #pragma unroll
        for (int q = 0; q < 16; q++) u[q] = 0;
      }
      u16x8* dst = (u16x8*)&Ws[srow][shalf*16];
      dst[0] = (u16x8){u[0],u[1],u[2],u[3],u[4],u[5],u[6],u[7]};
      dst[1] = (u16x8){u[8],u[9],u[10],u[11],u[12],u[13],u[14],u[15]};
    }
    __syncthreads();
    bf16x8 af[4], bw[4];
    #pragma unroll
    for (int i = 0; i < 4; i++)
      af[i] = *(const bf16x8*)&As[wr*64 + i*16 + fr][kc*8];
    #pragma unroll
    for (int j = 0; j < 4; j++)
      bw[j] = *(const bf16x8*)&Ws[wc*64 + j*16 + fr][kc*8];
    #pragma unroll
    for (int i = 0; i < 4; i++)
      #pragma unroll
      for (int j = 0; j < 4; j++)
        acc[i][j] = __builtin_amdgcn_mfma_f32_16x16x32_bf16(af[i], bw[j], acc[i][j], 0, 0, 0);
    __syncthreads();
  }

  float alpha = 1.f, cst = 0.f;
  if (MODE == 3 || MODE == 4){
    const float* mt = mtl + (long)s*3;
    alpha = 0.5f*expf(-mt[mtlIdx]);
    if (MODE == 3) cst = mt[0] + mt[1] + mt[2];
  }
  int cr4 = (lane >> 4)*4, ccol = lane & 15;
  #pragma unroll
  for (int j = 0; j < 4; j++){
    int gn = n0 + wc*64 + j*16 + ccol;
    if (gn >= Nc) continue;
    float bv = bias ? bias[gn] : 0.f;
    #pragma unroll
    for (int i = 0; i < 4; i++){
      int gmB = m0 + wr*64 + i*16 + cr4;
      #pragma unroll
      for (int r = 0; r < 4; r++){
        int gm = gmB + r;
        if (gm >= M) continue;
        float v = acc[i][j][r] + bv;
        long off = (long)gm*Nc + gn;
        if      (MODE == 0) C[off] = v;
        else if (MODE == 1) C[off] = fmaxf(v, 0.f);
        else if (MODE == 2) C[off] += v;
        else if (MODE == 3) C[off] = alpha*v + cst;
        else                C[off] += alpha*v;
      }
    }
  }
}

// ---------------- 3x3 attention, NH=2 heads of 256 ----------------
__global__ void attn_k(const float* __restrict__ qkv, float* __restrict__ o){
  int s = blockIdx.z, m = blockIdx.x, h = blockIdx.y;
  const float* base = qkv + (long)s*QKV_S + (long)m*3*1536 + (long)h*256;
  int t = threadIdx.x;
  float q[3], k[3], v[3];
  #pragma unroll
  for (int i = 0; i < 3; i++){
    q[i] = base[(long)i*1536 + t];
    k[i] = base[(long)i*1536 + 512 + t];
    v[i] = base[(long)i*1536 + 1024 + t];
  }
  __shared__ float sm[4];
  __shared__ float att[9];
  #pragma unroll
  for (int i = 0; i < 3; i++)
    #pragma unroll
    for (int j = 0; j < 3; j++){
      float p = q[i]*k[j];
      for (int off = 32; off; off >>= 1) p += __shfl_down(p, off);
      __syncthreads();
      if ((t & 63) == 0) sm[t >> 6] = p;
      __syncthreads();
      if (t == 0) att[i*3 + j] = (sm[0]+sm[1]+sm[2]+sm[3]) * 0.0625f; // 256^-0.5
    }
  __syncthreads();
  if (t < 3){
    float a = att[t*3], b = att[t*3+1], c = att[t*3+2];
    float mx = fmaxf(a, fmaxf(b, c));
    a = expf(a-mx); b = expf(b-mx); c = expf(c-mx);
    float inv = 1.f/(a+b+c);
    att[t*3] = a*inv; att[t*3+1] = b*inv; att[t*3+2] = c*inv;
  }
  __syncthreads();
  float* ob = o + (long)s*Z_S + (long)m*3*512 + (long)h*256;
  #pragma unroll
  for (int i = 0; i < 3; i++)
    ob[(long)i*512 + t] = att[i*3]*v[0] + att[i*3+1]*v[1] + att[i*3+2]*v[2];
}

// ---------------- z = LN(z + t) over 512 ----------------
__global__ void add_ln_k(float* __restrict__ z, const float* __restrict__ tbuf,
                         const float* __restrict__ w, const float* __restrict__ b,
                         long zs, long ts, long wstr){
  int s = blockIdx.z; long r = blockIdx.x;
  float* zr = z + (long)s*zs + r*HH;
  const float* tr = tbuf + (long)s*ts + r*HH;
  const float* wr = w + (long)s*wstr;
  const float* br = b + (long)s*wstr;
  int d0 = threadIdx.x, d1 = threadIdx.x + 256;
  float x0 = zr[d0] + tr[d0], x1 = zr[d1] + tr[d1];
  __shared__ float sm[4];
  float tsum = x0 + x1;
  for (int off = 32; off; off >>= 1) tsum += __shfl_down(tsum, off);
  if ((threadIdx.x & 63) == 0) sm[threadIdx.x >> 6] = tsum;
  __syncthreads();
  float mean = (sm[0]+sm[1]+sm[2]+sm[3]) * (1.f/512.f);
  float e0 = x0 - mean, e1 = x1 - mean;
  float vs = e0*e0 + e1*e1;
  __syncthreads();
  for (int off = 32; off; off >>= 1) vs += __shfl_down(vs, off);
  if ((threadIdx.x & 63) == 0) sm[threadIdx.x >> 6] = vs;
  __syncthreads();
  float var = (sm[0]+sm[1]+sm[2]+sm[3]) * (1.f/512.f);
  float inv = 1.f/sqrtf(var + 1e-5f);
  zr[d0] = e0*inv*wr[d0] + br[d0];
  zr[d1] = e1*inv*wr[d1] + br[d1];
}

// ---------------- leaf LSTM cell ----------------
__global__ void leaf_k(const float* __restrict__ iou, const float* __restrict__ c0,
                       float* hbuf, float* cbuf){
  int s = blockIdx.z, p = blockIdx.x;
  int tree = p / 729, j = p - tree*729;
  long row = (long)(tree*NPT + 364 + j)*512;
  const float* iour = iou + (long)s*QKV_S + (long)p*1536;
  const float* c0r = c0 + (long)s*H_S + row;
  for (int d = threadIdx.x; d < 512; d += 256){
    float cn = sigm(iour[d]) * tanhf(iour[1024 + d]) + c0r[d];
    float hn = sigm(iour[512 + d]) * tanhf(cn);
    hbuf[(long)s*H_S + row + d] = hn;
    cbuf[(long)s*H_S + row + d] = cn;
  }
}

// ---------------- internal-node combine ----------------
__global__ void combine_k(const float* __restrict__ iou, const float* __restrict__ hc,
                          const float* __restrict__ wx, const float* __restrict__ bfv,
                          const float* cbuf, float* hbuf, float* cout,
                          int n, int st, int cs){
  int s = blockIdx.z, p = blockIdx.x;
  int tree = p / n, j = p - tree*n;
  const float* iour = iou + (long)s*QKV_S + (long)p*1536;
  const float* hcr  = hc  + (long)s*Z_S  + (long)p*1536;
  const float* wxr  = wx  + (long)s*WX_S + (long)p*512;
  const float* bfr  = bfv + (long)s*512;
  const float* cch  = cbuf + (long)s*H_S + (long)(tree*NPT + cs + 3*j)*512;
  long orow = (long)s*H_S + (long)(tree*NPT + st + j)*512;
  for (int d = threadIdx.x; d < 512; d += 256){
    float wv = wxr[d] + bfr[d];
    float cpre = 0.f;
    #pragma unroll
    for (int ch = 0; ch < 3; ch++){
      float fg = sigm(wv + hcr[ch*512 + d]);
      cpre += fg * cch[ch*512 + d];
    }
    float iv = iour[d], ov = iour[512 + d], uv = iour[1024 + d];
    float cn = sigm(iv)*tanhf(uv) + cpre;
    float hn = sigm(ov)*tanhf(cn);
    hbuf[orow + d] = hn;
    cout[orow + d] = cn;
  }
}

#define GEMM(MODE, A, W, BI, CC, M, Nc, K, sA, sW, sB, sC, MTL, IDX)                    \
  mgemm_k<MODE><<<dim3(((Nc)+127)/128, ((M)+127)/128, SIDES), 256, 0, stream>>>(        \
      A, W, BI, CC, M, Nc, K, sA, sW, sB, sC, MTL, IDX)

extern "C" void kernel_launch(void* const* d_in, const int* in_sizes, int n_in,
                              void* d_out, int out_size, void* d_ws, size_t ws_size,
                              hipStream_t stream){
  (void)in_sizes; (void)n_in; (void)out_size;
  const int*   user_ids  = (const int*)d_in[0];
  const int*   feat_ids  = (const int*)d_in[1];
  const int*   time_ids  = (const int*)d_in[2];
  const int*   mask      = (const int*)d_in[3];
  const float* user_emb  = (const float*)d_in[6];
  const float* fuse_emb  = (const float*)d_in[7];
  const float* time_pe   = (const float*)d_in[8];
  const float* Wf        = (const float*)d_in[9];
  const float* bf        = (const float*)d_in[10];
  const float* Wiou      = (const float*)d_in[11];
  const float* Uiou      = (const float*)d_in[12];
  const float* biou      = (const float*)d_in[13];
  const float* attn_in_w = (const float*)d_in[14];
  const float* attn_in_b = (const float*)d_in[15];
  const float* attn_out_w= (const float*)d_in[16];
  const float* attn_out_b= (const float*)d_in[17];
  const float* ff1_w     = (const float*)d_in[18];
  const float* ff1_b     = (const float*)d_in[19];
  const float* ff2_w     = (const float*)d_in[20];
  const float* ff2_b     = (const float*)d_in[21];
  const float* ln1_w     = (const float*)d_in[22];
  const float* ln1_b     = (const float*)d_in[23];
  const float* ln2_w     = (const float*)d_in[24];
  const float* ln2_b     = (const float*)d_in[25];
  const float* dec_poi_w = (const float*)d_in[26];
  const float* dec_poi_b = (const float*)d_in[27];
  const float* dec_cat_w = (const float*)d_in[28];
  const float* dec_cat_b = (const float*)d_in[29];
  const float* dec_coo_w = (const float*)d_in[30];
  const float* dec_coo_b = (const float*)d_in[31];
  const float* cat2poi_w = (const float*)d_in[32];
  const float* cat2poi_b = (const float*)d_in[33];
  const float* coo2poi_w = (const float*)d_in[34];
  const float* coo2poi_b = (const float*)d_in[35];
  const float* mtl       = (const float*)d_in[36];
  const float* c0        = (const float*)d_in[37];

  float* out = (float*)d_out;
  float* ws  = (float*)d_ws;

  // H and C always live in ws. Remaining scratch: ws if big enough,
  // else the side-0 poi region of d_out (written only at the very end).
  float* Hb = ws;
  float* Cb = ws + 2*H_S;
  float *QKV, *Zb, *TMP, *Xb, *XLb, *WXb;
  size_t need = (size_t)(2*(2*H_S + 2*Z_S + QKV_S + X_S + XL_S + WX_S))*4;
  if (ws_size >= need){
    float* p = ws + 4*H_S;
    QKV = p; p += 2*QKV_S;
    Zb  = p; p += 2*Z_S;
    TMP = p; p += 2*Z_S;
    Xb  = p; p += 2*X_S;
    XLb = p; p += 2*XL_S;
    WXb = p;
  } else {
    QKV = out + 0L;
    Zb  = out + 17915904L;
    TMP = out + 23887872L;
    Xb  = out + 29859840L;
    XLb = out + 34336768L;
    WXb = out + 37322752L;
  }

  // 1) embeddings -> X
  embed_k<<<dim3(NN,1,SIDES), 256, 0, stream>>>(user_ids, feat_ids, time_ids, mask,
                                                user_emb, fuse_emb, time_pe, Xb);

  // 2) leaves: gather x rows, iou0 = x@Wiou^T (no bias), LSTM cell
  gather_rows_k<<<dim3(NTREE*729,1,SIDES), 256, 0, stream>>>(XLb, Xb, 729, 364, EE, XL_S, X_S);
  GEMM(0, XLb, Wiou, (const float*)nullptr, QKV, 5832, 1536, 256,
       XL_S, (long)1536*256, 0L, QKV_S, (const float*)nullptr, 0);
  leaf_k<<<dim3(5832,1,SIDES), 256, 0, stream>>>(QKV, c0, Hb, Cb);

  const int p3[7]   = {1,3,9,27,81,243,729};
  const int offs[7] = {0,1,4,13,40,121,364};

  // 3) internal levels, bottom-up
  for (int l = 5; l >= 0; l--){
    int n = p3[l], st = offs[l], cs = offs[l+1];
    int P = NTREE*n, T = 3*P;
    gather_rows_k<<<dim3(T,1,SIDES), 256, 0, stream>>>(Zb, Hb, 3*n, cs, HH, Z_S, H_S);
    for (int L = 0; L < LAYERS; L++){
      GEMM(0, Zb, attn_in_w + (long)L*1536*512, attn_in_b + (long)L*1536, QKV,
           T, 1536, 512, Z_S, (long)LAYERS*1536*512, (long)LAYERS*1536, QKV_S,
           (const float*)nullptr, 0);
      attn_k<<<dim3(P,2,SIDES), 256, 0, stream>>>(QKV, TMP);
      GEMM(0, TMP, attn_out_w + (long)L*512*512, attn_out_b + (long)L*512, QKV,
           T, 512, 512, Z_S, (long)LAYERS*512*512, (long)LAYERS*512, QKV_S,
           (const float*)nullptr, 0);
      add_ln_k<<<dim3(T,1,SIDES), 256, 0, stream>>>(Zb, QKV,
           ln1_w + (long)L*512, ln1_b + (long)L*512, Z_S, QKV_S, (long)LAYERS*512);
      GEMM(1, Zb, ff1_w + (long)L*512*512, ff1_b + (long)L*512, TMP,
           T, 512, 512, Z_S, (long)LAYERS*512*512, (long)LAYERS*512, Z_S,
           (const float*)nullptr, 0);
      GEMM(0, TMP, ff2_w + (long)L*512*512, ff2_b + (long)L*512, QKV,
           T, 512, 512, Z_S, (long)LAYERS*512*512, (long)LAYERS*512, QKV_S,
           (const float*)nullptr, 0);
      add_ln_k<<<dim3(T,1,SIDES), 256, 0, stream>>>(Zb, QKV,
           ln2_w + (long)L*512, ln2_b + (long)L*512, Z_S, QKV_S, (long)LAYERS*512);
    }
    gather_rows_k<<<dim3(P,1,SIDES), 256, 0, stream>>>(XLb, Xb, n, st, EE, XL_S, X_S);
    GEMM(0, XLb, Wf, (const float*)nullptr, WXb, P, 512, 256,
         XL_S, (long)512*256, 0L, WX_S, (const float*)nullptr, 0);
    GEMM(0, XLb, Wiou, biou, QKV, P, 1536, 256,
         XL_S, (long)1536*256, 1536L, QKV_S, (const float*)nullptr, 0);
    GEMM(2, Zb, Uiou, (const float*)nullptr, QKV, P, 1536, 1536,
         Z_S, (long)1536*1536, 0L, QKV_S, (const float*)nullptr, 0);
    combine_k<<<dim3(P,1,SIDES), 256, 0, stream>>>(QKV, Zb, WXb, bf, Cb, Hb, Cb, n, st, cs);
  }

  // 4) decoders
  GEMM(0, Hb, dec_cat_w, dec_cat_b, out + CAT_OFF, NN, NCAT, HH,
       H_S, (long)NCAT*HH, (long)NCAT, OUT_S, (const float*)nullptr, 0);
  GEMM(0, Hb, dec_coo_w, dec_coo_b, out + COO_OFF, NN, NCOO, HH,
       H_S, (long)NCOO*HH, (long)NCOO, OUT_S, (const float*)nullptr, 0);
  GEMM(3, Hb, dec_poi_w, dec_poi_b, out, NN, NPOI, HH,
       H_S, (long)NPOI*HH, (long)NPOI, OUT_S, mtl, 0);
  GEMM(4, out + CAT_OFF, cat2poi_w, cat2poi_b, out, NN, NPOI, NCAT,
       OUT_S, (long)NPOI*NCAT, (long)NPOI, OUT_S, mtl, 1);
  GEMM(4, out + COO_OFF, coo2poi_w, coo2poi_b, out, NN, NPOI, NCOO,
       OUT_S, (long)NPOI*NCOO, (long)NPOI, OUT_S, mtl, 2);
}

// Round 3
// 3755.800 us; speedup vs baseline: 2.9282x; 1.3616x over previous
//
#include <hip/hip_runtime.h>
#include <math.h>

#define SIDES 2
#define LAYERS 2
#define NTREE 8
#define NPT 1093
#define NN (NTREE*NPT)        // 8744
#define EE 256
#define HH 512
#define NUSERS 2000
#define NPOI 5000
#define NCAT 300
#define NCOO 50
#define FUSEN 5350
#define TMAXN 600
#define TOKMAX 5832           // 8*729
#define PARMAX 1944           // 8*243

// side strides (floats)
constexpr long X_S   = (long)NN*EE;
constexpr long H_S   = (long)NN*HH;
constexpr long Z_S   = (long)TOKMAX*HH;
constexpr long QKV_S = (long)TOKMAX*3*HH;
constexpr long XL_S  = (long)TOKMAX*EE;
constexpr long WX_S  = (long)PARMAX*HH;

constexpr long OUT_S   = 46780400L;   // per-side output block
constexpr long CAT_OFF = 43720000L;
constexpr long COO_OFF = 46343200L;

constexpr long WEFF_S  = (long)NPOI*HH;      // 2,560,000
constexpr long DCT_S   = (long)HH*NCAT;      // 153,600
constexpr long DCO_S   = (long)HH*NCOO;      // 25,600

typedef __attribute__((ext_vector_type(8))) short  bf16x8;
typedef __attribute__((ext_vector_type(8))) ushort u16x8;
typedef __attribute__((ext_vector_type(4))) float  f32x4;

__device__ __forceinline__ float sigm(float x){ return 1.f/(1.f+expf(-x)); }

__device__ __forceinline__ ushort f2b(float f){
  union { float f; unsigned u; } v; v.f = f;
  unsigned r = (v.u + 0x7fffu + ((v.u >> 16) & 1u)) >> 16;
  return (ushort)r;
}

// ---------------- embedding ----------------
__global__ void embed_k(const int* __restrict__ uid, const int* __restrict__ fid,
                        const int* __restrict__ tid, const int* __restrict__ mask,
                        const float* __restrict__ uemb, const float* __restrict__ femb,
                        const float* __restrict__ tpe, float* __restrict__ X){
  int s = blockIdx.z; long i = blockIdx.x; int d = threadIdx.x;
  int m = mask[(long)s*NN + i];
  int u = uid[(long)s*NN + i]*m, f = fid[(long)s*NN + i]*m, t = tid[(long)s*NN + i]*m;
  float e = (d < 128) ? uemb[((long)s*NUSERS + u)*128 + d]
                      : femb[((long)s*FUSEN + f)*128 + (d-128)];
  e += 0.5f * tpe[((long)s*TMAXN + t)*256 + d];
  X[(long)s*X_S + i*EE + d] = e * (float)m;
}

// ---------------- row gather (tree-strided -> dense) ----------------
__global__ void gather_rows_k(float* __restrict__ dst, const float* __restrict__ src,
                              int rows_per_tree, int src_off, int cols,
                              long sDst, long sSrc){
  int s = blockIdx.z; int r = blockIdx.x;
  int tree = r / rows_per_tree, w = r - tree*rows_per_tree;
  const float* sp = src + (long)s*sSrc + (long)(tree*NPT + src_off + w)*cols;
  float* dp = dst + (long)s*sDst + (long)r*cols;
  for (int d = threadIdx.x; d < cols; d += blockDim.x) dp[d] = sp[d];
}

// ---------------- bf16 MFMA GEMM: C = epilogue(A @ W^T + bias) ----------------
// A: [M][K] f32, W: [Nc][K] f32 (converted to bf16 during staging).
// MFMA operands swapped (W as A-operand) so each lane's 4 acc regs span 4
// consecutive N columns at fixed M row -> f32x4 stores when Nc%4==0.
// MODE 0: C = acc+bias; 1: relu; 2: C += acc(+bias); 4: C += a_idx*(acc+bias)
template<int MODE>
__global__ void __launch_bounds__(256)
mgemm_k(const float* __restrict__ A, const float* __restrict__ W,
        const float* __restrict__ bias, float* __restrict__ C,
        int M, int Nc, int K,
        long sA, long sW, long sB, long sC,
        const float* __restrict__ mtl, int mtlIdx){
  int s = blockIdx.z;
  A += (long)s*sA; W += (long)s*sW; C += (long)s*sC;
  if (bias) bias += (long)s*sB;
  __shared__ ushort As[128][40];   // stride 40 elems (80B)
  __shared__ ushort Ws[128][40];
  int tid = threadIdx.x;
  int lane = tid & 63, wave = tid >> 6;
  int wr = wave >> 1, wc = wave & 1;           // 2x2 waves of 64x64
  int m0 = blockIdx.y*128, n0 = blockIdx.x*128;
  int srow = tid >> 1, shalf = tid & 1;        // staging: row, k-half (16 elems)
  bool al16 = ((K & 3) == 0);
  f32x4 acc[4][4];
  #pragma unroll
  for (int i = 0; i < 4; i++)
    #pragma unroll
    for (int j = 0; j < 4; j++) acc[i][j] = (f32x4){0.f,0.f,0.f,0.f};

  int fr = lane & 15, kc = lane >> 4;

  for (int k0 = 0; k0 < K; k0 += 32){
    int kb = k0 + shalf*16;
    // stage A rows
    {
      int gm = m0 + srow;
      ushort u[16];
      if (gm < M){
        const float* ap = A + (long)gm*K + kb;
        #pragma unroll
        for (int q = 0; q < 4; q++){
          int gk = kb + q*4;
          if (al16 && gk + 3 < K){
            f32x4 t = *(const f32x4*)(ap + q*4);
            u[q*4+0]=f2b(t[0]); u[q*4+1]=f2b(t[1]); u[q*4+2]=f2b(t[2]); u[q*4+3]=f2b(t[3]);
          } else {
            #pragma unroll
            for (int e = 0; e < 4; e++)
              u[q*4+e] = (gk+e < K) ? f2b(ap[q*4+e]) : (ushort)0;
          }
        }
      } else {
        #pragma unroll
        for (int q = 0; q < 16; q++) u[q] = 0;
      }
      u16x8* dst = (u16x8*)&As[srow][shalf*16];
      dst[0] = (u16x8){u[0],u[1],u[2],u[3],u[4],u[5],u[6],u[7]};
      dst[1] = (u16x8){u[8],u[9],u[10],u[11],u[12],u[13],u[14],u[15]};
    }
    // stage W rows
    {
      int gn = n0 + srow;
      ushort u[16];
      if (gn < Nc){
        const float* wp = W + (long)gn*K + kb;
        #pragma unroll
        for (int q = 0; q < 4; q++){
          int gk = kb + q*4;
          if (al16 && gk + 3 < K){
            f32x4 t = *(const f32x4*)(wp + q*4);
            u[q*4+0]=f2b(t[0]); u[q*4+1]=f2b(t[1]); u[q*4+2]=f2b(t[2]); u[q*4+3]=f2b(t[3]);
          } else {
            #pragma unroll
            for (int e = 0; e < 4; e++)
              u[q*4+e] = (gk+e < K) ? f2b(wp[q*4+e]) : (ushort)0;
          }
        }
      } else {
        #pragma unroll
        for (int q = 0; q < 16; q++) u[q] = 0;
      }
      u16x8* dst = (u16x8*)&Ws[srow][shalf*16];
      dst[0] = (u16x8){u[0],u[1],u[2],u[3],u[4],u[5],u[6],u[7]};
      dst[1] = (u16x8){u[8],u[9],u[10],u[11],u[12],u[13],u[14],u[15]};
    }
    __syncthreads();
    bf16x8 af[4], bw[4];
    #pragma unroll
    for (int i = 0; i < 4; i++)
      af[i] = *(const bf16x8*)&As[wr*64 + i*16 + fr][kc*8];
    #pragma unroll
    for (int j = 0; j < 4; j++)
      bw[j] = *(const bf16x8*)&Ws[wc*64 + j*16 + fr][kc*8];
    // swapped operands: D rows <- W (N dim), D cols <- A (M dim)
    #pragma unroll
    for (int i = 0; i < 4; i++)
      #pragma unroll
      for (int j = 0; j < 4; j++)
        acc[i][j] = __builtin_amdgcn_mfma_f32_16x16x32_bf16(bw[j], af[i], acc[i][j], 0, 0, 0);
    __syncthreads();
  }

  float alpha = 1.f;
  if (MODE == 4){
    const float* mt = mtl + (long)s*3;
    alpha = 0.5f*expf(-mt[mtlIdx]);
  }
  int ccol = lane & 15, cr4 = (lane >> 4)*4;
  bool vecN = ((Nc & 3) == 0);
  #pragma unroll
  for (int i = 0; i < 4; i++){
    int gm = m0 + wr*64 + i*16 + ccol;
    if (gm >= M) continue;
    long rowoff = (long)gm*Nc;
    #pragma unroll
    for (int j = 0; j < 4; j++){
      int gn0 = n0 + wc*64 + j*16 + cr4;
      if (gn0 >= Nc) continue;
      if (vecN){
        f32x4 v = acc[i][j];
        if (bias){ f32x4 bv = *(const f32x4*)&bias[gn0]; v += bv; }
        f32x4* cp = (f32x4*)&C[rowoff + gn0];
        if      (MODE == 0) *cp = v;
        else if (MODE == 1) *cp = (f32x4){fmaxf(v[0],0.f),fmaxf(v[1],0.f),fmaxf(v[2],0.f),fmaxf(v[3],0.f)};
        else if (MODE == 2) { f32x4 o = *cp; *cp = o + v; }
        else                { f32x4 o = *cp; *cp = o + alpha*v; }
      } else {
        #pragma unroll
        for (int r = 0; r < 4; r++){
          int gn = gn0 + r;
          if (gn >= Nc) continue;
          float v = acc[i][j][r] + (bias ? bias[gn] : 0.f);
          long off = rowoff + gn;
          if      (MODE == 0) C[off] = v;
          else if (MODE == 1) C[off] = fmaxf(v, 0.f);
          else if (MODE == 2) C[off] += v;
          else                C[off] += alpha*v;
        }
      }
    }
  }
}

// ---------------- decoder fusion precompute ----------------
// dst[cols][rows] = src[rows][cols]^T per side
__global__ void transpose_k(float* __restrict__ dst, const float* __restrict__ src,
                            int rows, int cols){
  int s = blockIdx.z; int k = blockIdx.x;   // k < cols
  src += (long)s*rows*cols; dst += (long)s*rows*cols;
  for (int r = threadIdx.x; r < rows; r += blockDim.x)
    dst[(long)k*rows + r] = src[(long)r*cols + k];
}

// W_eff = a0 * dec_poi_w (elementwise init)
__global__ void weff_init_k(float* __restrict__ weff, const float* __restrict__ poi_w,
                            const float* __restrict__ mtl){
  int s = blockIdx.z;
  long idx = (long)blockIdx.x*blockDim.x + threadIdx.x;
  float a0 = 0.5f*expf(-mtl[(long)s*3]);
  weff[(long)s*WEFF_S + idx] = a0 * poi_w[(long)s*WEFF_S + idx];
}

// b_eff[n] = a0*poi_b + a1*(cat2poi@cat_b + cat2poi_b) + a2*(coo2poi@coo_b + coo2poi_b) + p0+p1+p2
__global__ void beff_k(float* __restrict__ beff, const float* __restrict__ poi_b,
                       const float* __restrict__ cat_b, const float* __restrict__ c2p_w,
                       const float* __restrict__ c2p_b, const float* __restrict__ coo_b,
                       const float* __restrict__ o2p_w, const float* __restrict__ o2p_b,
                       const float* __restrict__ mtl){
  int s = blockIdx.z;
  int n = blockIdx.x*blockDim.x + threadIdx.x;
  if (n >= NPOI) return;
  const float* mt = mtl + (long)s*3;
  float a0 = 0.5f*expf(-mt[0]), a1 = 0.5f*expf(-mt[1]), a2 = 0.5f*expf(-mt[2]);
  float acc1 = 0.f, acc2 = 0.f;
  for (int c = 0; c < NCAT; c++)
    acc1 += cat_b[(long)s*NCAT + c] * c2p_w[((long)s*NPOI + n)*NCAT + c];
  for (int c = 0; c < NCOO; c++)
    acc2 += coo_b[(long)s*NCOO + c] * o2p_w[((long)s*NPOI + n)*NCOO + c];
  beff[(long)s*NPOI + n] = a0*poi_b[(long)s*NPOI + n]
      + a1*(acc1 + c2p_b[(long)s*NPOI + n]) + a2*(acc2 + o2p_b[(long)s*NPOI + n])
      + mt[0] + mt[1] + mt[2];
}

// ---------------- 3x3 attention, NH=2 heads of 256 ----------------
__global__ void attn_k(const float* __restrict__ qkv, float* __restrict__ o){
  int s = blockIdx.z, m = blockIdx.x, h = blockIdx.y;
  const float* base = qkv + (long)s*QKV_S + (long)m*3*1536 + (long)h*256;
  int t = threadIdx.x;
  float q[3], k[3], v[3];
  #pragma unroll
  for (int i = 0; i < 3; i++){
    q[i] = base[(long)i*1536 + t];
    k[i] = base[(long)i*1536 + 512 + t];
    v[i] = base[(long)i*1536 + 1024 + t];
  }
  __shared__ float sm[4];
  __shared__ float att[9];
  #pragma unroll
  for (int i = 0; i < 3; i++)
    #pragma unroll
    for (int j = 0; j < 3; j++){
      float p = q[i]*k[j];
      for (int off = 32; off; off >>= 1) p += __shfl_down(p, off);
      __syncthreads();
      if ((t & 63) == 0) sm[t >> 6] = p;
      __syncthreads();
      if (t == 0) att[i*3 + j] = (sm[0]+sm[1]+sm[2]+sm[3]) * 0.0625f; // 256^-0.5
    }
  __syncthreads();
  if (t < 3){
    float a = att[t*3], b = att[t*3+1], c = att[t*3+2];
    float mx = fmaxf(a, fmaxf(b, c));
    a = expf(a-mx); b = expf(b-mx); c = expf(c-mx);
    float inv = 1.f/(a+b+c);
    att[t*3] = a*inv; att[t*3+1] = b*inv; att[t*3+2] = c*inv;
  }
  __syncthreads();
  float* ob = o + (long)s*Z_S + (long)m*3*512 + (long)h*256;
  #pragma unroll
  for (int i = 0; i < 3; i++)
    ob[(long)i*512 + t] = att[i*3]*v[0] + att[i*3+1]*v[1] + att[i*3+2]*v[2];
}

// ---------------- z = LN(z + t) over 512 ----------------
__global__ void add_ln_k(float* __restrict__ z, const float* __restrict__ tbuf,
                         const float* __restrict__ w, const float* __restrict__ b,
                         long zs, long ts, long wstr){
  int s = blockIdx.z; long r = blockIdx.x;
  float* zr = z + (long)s*zs + r*HH;
  const float* tr = tbuf + (long)s*ts + r*HH;
  const float* wr = w + (long)s*wstr;
  const float* br = b + (long)s*wstr;
  int d0 = threadIdx.x, d1 = threadIdx.x + 256;
  float x0 = zr[d0] + tr[d0], x1 = zr[d1] + tr[d1];
  __shared__ float sm[4];
  float tsum = x0 + x1;
  for (int off = 32; off; off >>= 1) tsum += __shfl_down(tsum, off);
  if ((threadIdx.x & 63) == 0) sm[threadIdx.x >> 6] = tsum;
  __syncthreads();
  float mean = (sm[0]+sm[1]+sm[2]+sm[3]) * (1.f/512.f);
  float e0 = x0 - mean, e1 = x1 - mean;
  float vs = e0*e0 + e1*e1;
  __syncthreads();
  for (int off = 32; off; off >>= 1) vs += __shfl_down(vs, off);
  if ((threadIdx.x & 63) == 0) sm[threadIdx.x >> 6] = vs;
  __syncthreads();
  float var = (sm[0]+sm[1]+sm[2]+sm[3]) * (1.f/512.f);
  float inv = 1.f/sqrtf(var + 1e-5f);
  zr[d0] = e0*inv*wr[d0] + br[d0];
  zr[d1] = e1*inv*wr[d1] + br[d1];
}

// ---------------- leaf LSTM cell ----------------
__global__ void leaf_k(const float* __restrict__ iou, const float* __restrict__ c0,
                       float* hbuf, float* cbuf){
  int s = blockIdx.z, p = blockIdx.x;
  int tree = p / 729, j = p - tree*729;
  long row = (long)(tree*NPT + 364 + j)*512;
  const float* iour = iou + (long)s*QKV_S + (long)p*1536;
  const float* c0r = c0 + (long)s*H_S + row;
  for (int d = threadIdx.x; d < 512; d += 256){
    float cn = sigm(iour[d]) * tanhf(iour[1024 + d]) + c0r[d];
    float hn = sigm(iour[512 + d]) * tanhf(cn);
    hbuf[(long)s*H_S + row + d] = hn;
    cbuf[(long)s*H_S + row + d] = cn;
  }
}

// ---------------- internal-node combine ----------------
__global__ void combine_k(const float* __restrict__ iou, const float* __restrict__ hc,
                          const float* __restrict__ wx, const float* __restrict__ bfv,
                          const float* cbuf, float* hbuf, float* cout,
                          int n, int st, int cs){
  int s = blockIdx.z, p = blockIdx.x;
  int tree = p / n, j = p - tree*n;
  const float* iour = iou + (long)s*QKV_S + (long)p*1536;
  const float* hcr  = hc  + (long)s*Z_S  + (long)p*1536;
  const float* wxr  = wx  + (long)s*WX_S + (long)p*512;
  const float* bfr  = bfv + (long)s*512;
  const float* cch  = cbuf + (long)s*H_S + (long)(tree*NPT + cs + 3*j)*512;
  long orow = (long)s*H_S + (long)(tree*NPT + st + j)*512;
  for (int d = threadIdx.x; d < 512; d += 256){
    float wv = wxr[d] + bfr[d];
    float cpre = 0.f;
    #pragma unroll
    for (int ch = 0; ch < 3; ch++){
      float fg = sigm(wv + hcr[ch*512 + d]);
      cpre += fg * cch[ch*512 + d];
    }
    float iv = iour[d], ov = iour[512 + d], uv = iour[1024 + d];
    float cn = sigm(iv)*tanhf(uv) + cpre;
    float hn = sigm(ov)*tanhf(cn);
    hbuf[orow + d] = hn;
    cout[orow + d] = cn;
  }
}

#define GEMM(MODE, A, W, BI, CC, M, Nc, K, sA, sW, sB, sC, MTL, IDX)                    \
  mgemm_k<MODE><<<dim3(((Nc)+127)/128, ((M)+127)/128, SIDES), 256, 0, stream>>>(        \
      A, W, BI, CC, M, Nc, K, sA, sW, sB, sC, MTL, IDX)

extern "C" void kernel_launch(void* const* d_in, const int* in_sizes, int n_in,
                              void* d_out, int out_size, void* d_ws, size_t ws_size,
                              hipStream_t stream){
  (void)in_sizes; (void)n_in; (void)out_size;
  const int*   user_ids  = (const int*)d_in[0];
  const int*   feat_ids  = (const int*)d_in[1];
  const int*   time_ids  = (const int*)d_in[2];
  const int*   mask      = (const int*)d_in[3];
  const float* user_emb  = (const float*)d_in[6];
  const float* fuse_emb  = (const float*)d_in[7];
  const float* time_pe   = (const float*)d_in[8];
  const float* Wf        = (const float*)d_in[9];
  const float* bf        = (const float*)d_in[10];
  const float* Wiou      = (const float*)d_in[11];
  const float* Uiou      = (const float*)d_in[12];
  const float* biou      = (const float*)d_in[13];
  const float* attn_in_w = (const float*)d_in[14];
  const float* attn_in_b = (const float*)d_in[15];
  const float* attn_out_w= (const float*)d_in[16];
  const float* attn_out_b= (const float*)d_in[17];
  const float* ff1_w     = (const float*)d_in[18];
  const float* ff1_b     = (const float*)d_in[19];
  const float* ff2_w     = (const float*)d_in[20];
  const float* ff2_b     = (const float*)d_in[21];
  const float* ln1_w     = (const float*)d_in[22];
  const float* ln1_b     = (const float*)d_in[23];
  const float* ln2_w     = (const float*)d_in[24];
  const float* ln2_b     = (const float*)d_in[25];
  const float* dec_poi_w = (const float*)d_in[26];
  const float* dec_poi_b = (const float*)d_in[27];
  const float* dec_cat_w = (const float*)d_in[28];
  const float* dec_cat_b = (const float*)d_in[29];
  const float* dec_coo_w = (const float*)d_in[30];
  const float* dec_coo_b = (const float*)d_in[31];
  const float* cat2poi_w = (const float*)d_in[32];
  const float* cat2poi_b = (const float*)d_in[33];
  const float* coo2poi_w = (const float*)d_in[34];
  const float* coo2poi_b = (const float*)d_in[35];
  const float* mtl       = (const float*)d_in[36];
  const float* c0        = (const float*)d_in[37];

  float* out = (float*)d_out;
  float* ws  = (float*)d_ws;

  // H and C always live in ws. Remaining scratch: ws if big enough,
  // else the side-0 poi region of d_out (written only at the very end).
  float* Hb = ws;
  float* Cb = ws + 2*H_S;
  float *QKV, *Zb, *TMP, *Xb, *XLb, *WXb;
  size_t need = (size_t)(2*(2*H_S + 2*Z_S + QKV_S + X_S + XL_S + WX_S))*4;
  if (ws_size >= need){
    float* p = ws + 4*H_S;
    QKV = p; p += 2*QKV_S;
    Zb  = p; p += 2*Z_S;
    TMP = p; p += 2*Z_S;
    Xb  = p; p += 2*X_S;
    XLb = p; p += 2*XL_S;
    WXb = p;
  } else {
    QKV = out + 0L;
    Zb  = out + 17915904L;
    TMP = out + 23887872L;
    Xb  = out + 29859840L;
    XLb = out + 34336768L;
    WXb = out + 37322752L;
  }
  // decoder-fusion scratch lives in the Cb region (dead after the tree loop)
  float* Weff = Cb;                              // 2 x 2,560,000
  float* dctT = Cb + 2*WEFF_S;                   // 2 x 153,600
  float* dcoT = Cb + 2*WEFF_S + 2*DCT_S;         // 2 x 25,600
  float* beff = Cb + 2*WEFF_S + 2*DCT_S + 2*DCO_S; // 2 x 5,000

  // 1) embeddings -> X
  embed_k<<<dim3(NN,1,SIDES), 256, 0, stream>>>(user_ids, feat_ids, time_ids, mask,
                                                user_emb, fuse_emb, time_pe, Xb);

  // 2) leaves
  gather_rows_k<<<dim3(NTREE*729,1,SIDES), 256, 0, stream>>>(XLb, Xb, 729, 364, EE, XL_S, X_S);
  GEMM(0, XLb, Wiou, (const float*)nullptr, QKV, 5832, 1536, 256,
       XL_S, (long)1536*256, 0L, QKV_S, (const float*)nullptr, 0);
  leaf_k<<<dim3(5832,1,SIDES), 256, 0, stream>>>(QKV, c0, Hb, Cb);

  const int p3[7]   = {1,3,9,27,81,243,729};
  const int offs[7] = {0,1,4,13,40,121,364};

  // 3) internal levels, bottom-up
  for (int l = 5; l >= 0; l--){
    int n = p3[l], st = offs[l], cs = offs[l+1];
    int P = NTREE*n, T = 3*P;
    gather_rows_k<<<dim3(T,1,SIDES), 256, 0, stream>>>(Zb, Hb, 3*n, cs, HH, Z_S, H_S);
    for (int L = 0; L < LAYERS; L++){
      GEMM(0, Zb, attn_in_w + (long)L*1536*512, attn_in_b + (long)L*1536, QKV,
           T, 1536, 512, Z_S, (long)LAYERS*1536*512, (long)LAYERS*1536, QKV_S,
           (const float*)nullptr, 0);
      attn_k<<<dim3(P,2,SIDES), 256, 0, stream>>>(QKV, TMP);
      GEMM(0, TMP, attn_out_w + (long)L*512*512, attn_out_b + (long)L*512, QKV,
           T, 512, 512, Z_S, (long)LAYERS*512*512, (long)LAYERS*512, QKV_S,
           (const float*)nullptr, 0);
      add_ln_k<<<dim3(T,1,SIDES), 256, 0, stream>>>(Zb, QKV,
           ln1_w + (long)L*512, ln1_b + (long)L*512, Z_S, QKV_S, (long)LAYERS*512);
      GEMM(1, Zb, ff1_w + (long)L*512*512, ff1_b + (long)L*512, TMP,
           T, 512, 512, Z_S, (long)LAYERS*512*512, (long)LAYERS*512, Z_S,
           (const float*)nullptr, 0);
      GEMM(0, TMP, ff2_w + (long)L*512*512, ff2_b + (long)L*512, QKV,
           T, 512, 512, Z_S, (long)LAYERS*512*512, (long)LAYERS*512, QKV_S,
           (const float*)nullptr, 0);
      add_ln_k<<<dim3(T,1,SIDES), 256, 0, stream>>>(Zb, QKV,
           ln2_w + (long)L*512, ln2_b + (long)L*512, Z_S, QKV_S, (long)LAYERS*512);
    }
    gather_rows_k<<<dim3(P,1,SIDES), 256, 0, stream>>>(XLb, Xb, n, st, EE, XL_S, X_S);
    GEMM(0, XLb, Wf, (const float*)nullptr, WXb, P, 512, 256,
         XL_S, (long)512*256, 0L, WX_S, (const float*)nullptr, 0);
    GEMM(0, XLb, Wiou, biou, QKV, P, 1536, 256,
         XL_S, (long)1536*256, 1536L, QKV_S, (const float*)nullptr, 0);
    GEMM(2, Zb, Uiou, (const float*)nullptr, QKV, P, 1536, 1536,
         Z_S, (long)1536*1536, 0L, QKV_S, (const float*)nullptr, 0);
    combine_k<<<dim3(P,1,SIDES), 256, 0, stream>>>(QKV, Zb, WXb, bf, Cb, Hb, Cb, n, st, cs);
  }

  // 4) decoders. cat/coo outputs first (unchanged math).
  GEMM(0, Hb, dec_cat_w, dec_cat_b, out + CAT_OFF, NN, NCAT, HH,
       H_S, (long)NCAT*HH, (long)NCAT, OUT_S, (const float*)nullptr, 0);
  GEMM(0, Hb, dec_coo_w, dec_coo_b, out + COO_OFF, NN, NCOO, HH,
       H_S, (long)NCOO*HH, (long)NCOO, OUT_S, (const float*)nullptr, 0);

  // fused poi decoder: W_eff = a0*dec_poi + a1*cat2poi@dec_cat + a2*coo2poi@dec_coo
  transpose_k<<<dim3(HH,1,SIDES), 256, 0, stream>>>(dctT, dec_cat_w, NCAT, HH);
  transpose_k<<<dim3(HH,1,SIDES), 256, 0, stream>>>(dcoT, dec_coo_w, NCOO, HH);
  weff_init_k<<<dim3((NPOI*HH)/256,1,SIDES), 256, 0, stream>>>(Weff, dec_poi_w, mtl);
  beff_k<<<dim3((NPOI+255)/256,1,SIDES), 256, 0, stream>>>(beff, dec_poi_b,
       dec_cat_b, cat2poi_w, cat2poi_b, dec_coo_b, coo2poi_w, coo2poi_b, mtl);
  GEMM(4, cat2poi_w, dctT, (const float*)nullptr, Weff, NPOI, HH, NCAT,
       (long)NPOI*NCAT, DCT_S, 0L, WEFF_S, mtl, 1);
  GEMM(4, coo2poi_w, dcoT, (const float*)nullptr, Weff, NPOI, HH, NCOO,
       (long)NPOI*NCOO, DCO_S, 0L, WEFF_S, mtl, 2);
  GEMM(0, Hb, Weff, beff, out, NN, NPOI, HH,
       H_S, WEFF_S, (long)NPOI, OUT_S, (const float*)nullptr, 0);
}

// Round 6
// 1652.738 us; speedup vs baseline: 6.6543x; 2.2725x over previous
//
#include <hip/hip_runtime.h>
#include <math.h>

#define SIDES 2
#define LAYERS 2
#define NTREE 8
#define NPT 1093
#define NN (NTREE*NPT)        // 8744
#define EE 256
#define HH 512
#define NUSERS 2000
#define NPOI 5000
#define NCAT 300
#define NCOO 50
#define FUSEN 5350
#define TMAXN 600
#define TOKMAX 5832           // 8*729
#define PARMAX 1944           // 8*243

constexpr long OUT_S   = 46780400L;   // per-side output block (floats)
constexpr long CAT_OFF = 43720000L;
constexpr long COO_OFF = 46343200L;

// element strides per side
constexpr long H_S    = (long)NN*HH;        // 4,476,928
constexpr long X_S    = (long)NN*EE;        // 2,238,464
constexpr long Z_S    = (long)TOKMAX*HH;    // 2,985,984
constexpr long QKV_S  = (long)TOKMAX*3*HH;  // 8,957,952
constexpr long WXI_S  = (long)PARMAX*2048;  // 3,981,312
constexpr long WEFF_S = (long)NPOI*HH;      // 2,560,000

typedef __attribute__((ext_vector_type(8))) short  bf16x8;
typedef __attribute__((ext_vector_type(8))) ushort u16x8;
typedef __attribute__((ext_vector_type(4))) ushort u16x4;
typedef __attribute__((ext_vector_type(4))) float  f32x4;

__device__ __forceinline__ float sigm(float x){ return 1.f/(1.f+expf(-x)); }
__device__ __forceinline__ ushort f2b(float f){
  union { float f; unsigned u; } v; v.f = f;
  return (ushort)((v.u + 0x7fffu + ((v.u >> 16) & 1u)) >> 16);
}
__device__ __forceinline__ float b2f(ushort u){
  union { unsigned u; float f; } v; v.u = (unsigned)u << 16; return v.f;
}

// ================= preconvert kernels =================
__global__ void mcvt_k(ushort* d0, const float* s0, long n0,
                       ushort* d1, const float* s1, long n1,
                       ushort* d2, const float* s2, long n2,
                       ushort* d3, const float* s3, long n3,
                       ushort* d4, const float* s4, long n4,
                       ushort* d5, const float* s5, long n5){
  long g4 = (long)blockIdx.x*blockDim.x + threadIdx.x;
  long i = g4*4;
  ushort* d; const float* s; long off;
  if      (i < n0){ d=d0; s=s0; off=i; }
  else if ((i-=n0) < n1){ d=d1; s=s1; off=i; }
  else if ((i-=n1) < n2){ d=d2; s=s2; off=i; }
  else if ((i-=n2) < n3){ d=d3; s=s3; off=i; }
  else if ((i-=n3) < n4){ d=d4; s=s4; off=i; }
  else if ((i-=n4) < n5){ d=d5; s=s5; off=i; }
  else return;
  f32x4 v = *(const f32x4*)(s + off);
  *(u16x4*)(d + off) = (u16x4){f2b(v[0]), f2b(v[1]), f2b(v[2]), f2b(v[3])};
}

// W_comb[2048][1792]: rows 0-511 = [Wf | 0], rows 512-2047 = [Wiou | Uiou]
__global__ void wcomb_k(ushort* __restrict__ dst, const float* __restrict__ Wf,
                        const float* __restrict__ Wiou, const float* __restrict__ Uiou){
  int s = blockIdx.z; int row = blockIdx.x; int col = blockIdx.y*256 + threadIdx.x;
  float v;
  if (row < 512) v = (col < 256) ? Wf[((long)s*512 + row)*256 + col] : 0.f;
  else {
    int r = row - 512;
    v = (col < 256) ? Wiou[((long)s*1536 + r)*256 + col]
                    : Uiou[((long)s*1536 + r)*1536 + (col-256)];
  }
  dst[(long)s*2048*1792 + (long)row*1792 + col] = f2b(v);
}

__global__ void bcomb_k(float* __restrict__ dst, const float* __restrict__ biou){
  int s = blockIdx.z; int c = blockIdx.x*256 + threadIdx.x;
  dst[(long)s*2048 + c] = (c < 512) ? 0.f : biou[(long)s*1536 + (c-512)];
}

// pad+convert: dst[rows][dcols] <- src[rows][scols] (zero pad)
__global__ void padcvt_k(ushort* __restrict__ dst, const float* __restrict__ src,
                         int rows, int scols, int dcols){
  int s = blockIdx.z; int r = blockIdx.x; int c = blockIdx.y*256 + threadIdx.x;
  if (c >= dcols) return;
  float v = (c < scols) ? src[((long)s*rows + r)*scols + c] : 0.f;
  dst[((long)s*rows + r)*dcols + c] = f2b(v);
}

// transpose+pad+convert: dst[512][dcols] <- src[srows][512]^T
__global__ void tpcvt_k(ushort* __restrict__ dst, const float* __restrict__ src,
                        int srows, int dcols){
  int s = blockIdx.z; int h = blockIdx.x; int c = threadIdx.x;
  float v = (c < srows) ? src[((long)s*srows + c)*512 + h] : 0.f;
  dst[((long)s*512 + h)*dcols + c] = f2b(v);
}

// Weff_bf init = a0 * dec_poi_w
__global__ void weffinit_k(ushort* __restrict__ dst, const float* __restrict__ poi_w,
                           const float* __restrict__ mtl){
  int s = blockIdx.z;
  long i = ((long)blockIdx.x*blockDim.x + threadIdx.x)*4;
  float a0 = 0.5f*expf(-mtl[(long)s*3]);
  f32x4 v = *(const f32x4*)(poi_w + (long)s*WEFF_S + i);
  *(u16x4*)(dst + (long)s*WEFF_S + i) =
      (u16x4){f2b(a0*v[0]), f2b(a0*v[1]), f2b(a0*v[2]), f2b(a0*v[3])};
}

__global__ void beff_k(float* __restrict__ beff, const float* __restrict__ poi_b,
                       const float* __restrict__ cat_b, const float* __restrict__ c2p_w,
                       const float* __restrict__ c2p_b, const float* __restrict__ coo_b,
                       const float* __restrict__ o2p_w, const float* __restrict__ o2p_b,
                       const float* __restrict__ mtl){
  int s = blockIdx.z;
  int n = blockIdx.x*blockDim.x + threadIdx.x;
  if (n >= NPOI) return;
  const float* mt = mtl + (long)s*3;
  float a0 = 0.5f*expf(-mt[0]), a1 = 0.5f*expf(-mt[1]), a2 = 0.5f*expf(-mt[2]);
  float acc1 = 0.f, acc2 = 0.f;
  for (int c = 0; c < NCAT; c++)
    acc1 += cat_b[(long)s*NCAT + c] * c2p_w[((long)s*NPOI + n)*NCAT + c];
  for (int c = 0; c < NCOO; c++)
    acc2 += coo_b[(long)s*NCOO + c] * o2p_w[((long)s*NPOI + n)*NCOO + c];
  beff[(long)s*NPOI + n] = a0*poi_b[(long)s*NPOI + n]
      + a1*(acc1 + c2p_b[(long)s*NPOI + n]) + a2*(acc2 + o2p_b[(long)s*NPOI + n])
      + mt[0] + mt[1] + mt[2];
}

// ================= embedding (bf16 out) =================
__global__ void embed_k(const int* __restrict__ uid, const int* __restrict__ fid,
                        const int* __restrict__ tid, const int* __restrict__ mask,
                        const float* __restrict__ uemb, const float* __restrict__ femb,
                        const float* __restrict__ tpe, ushort* __restrict__ X){
  int s = blockIdx.z; long i = blockIdx.x; int d = threadIdx.x;
  int m = mask[(long)s*NN + i];
  int u = uid[(long)s*NN + i]*m, f = fid[(long)s*NN + i]*m, t = tid[(long)s*NN + i]*m;
  float e = (d < 128) ? uemb[((long)s*NUSERS + u)*128 + d]
                      : femb[((long)s*FUSEN + f)*128 + (d-128)];
  e += 0.5f * tpe[((long)s*TMAXN + t)*256 + d];
  X[(long)s*X_S + i*EE + d] = f2b(e * (float)m);
}

// ================= bf16 MFMA GEMM =================
// C = epilogue(A @ W^T + bias); A,W bf16; C f32 or bf16.
// A dual-source: k<kSplit from A1 (optionally tree-row-mapped), else A2 (dense rows).
// MODE 0: store(+bias); 1: relu; 4: C += alpha*acc  [alpha = 0.5*exp(-mtl[idx])]
template<int MODE, bool OBF>
__global__ void __launch_bounds__(256)
mgemm_k(const ushort* __restrict__ A1, long lda1, long sA1,
        const ushort* __restrict__ A2, long lda2, long sA2,
        int kSplit, int mapN, int mapOff,
        const ushort* __restrict__ Wt, long ldw, long sW,
        const float* __restrict__ bias, long sB,
        void* __restrict__ Cv, long ldc, long sC,
        int M, int Nc, int K, int nbx,
        const float* __restrict__ mtl, int mtlIdx){
  int s = blockIdx.z;
  A1 += (long)s*sA1; A2 += (long)s*sA2; Wt += (long)s*sW;
  if (bias) bias += (long)s*sB;

  // bijective xcd swizzle (m204)
  int flat = blockIdx.x, nwg = gridDim.x;
  int xcd = flat & 7, q = nwg >> 3, r8 = nwg & 7;
  int nf = (xcd < r8 ? xcd*(q+1) : r8*(q+1) + (xcd - r8)*q) + (flat >> 3);
  int bx = nf % nbx, by = nf / nbx;
  int m0 = by*128, n0 = bx*128;

  __shared__ ushort As[128*64];
  __shared__ ushort Ws[128*64];

  int tid = threadIdx.x;
  int lane = tid & 63, wave = tid >> 6;
  int wr = wave >> 1, wc = wave & 1;
  int fr = lane & 15, kc = lane >> 4;

  // staging: chunk c covers row = (tid>>3)+32c, 8-elem col group c16 = tid&7
  int baseRow = tid >> 3;
  int c16 = tid & 7;
  int col8 = c16*8;
  int swz = (baseRow & 7) << 4;

  long gA1[4], gA2[4], gW[4];
  int wbyte[4];
  #pragma unroll
  for (int c = 0; c < 4; c++){
    int row = baseRow + c*32;
    int ra = m0 + row; if (ra > M-1) ra = M-1;
    gA2[c] = ra;                                   // dense (A2)
    if (mapN > 0){ int tr = ra / mapN; gA1[c] = (long)(tr*NPT + mapOff + (ra - tr*mapN)); }
    else gA1[c] = ra;                              // mapped (A1)
    int rw = n0 + row; if (rw > Nc-1) rw = Nc-1;
    gW[c] = rw;
    wbyte[c] = row*128 + ((c16*16) ^ swz);
  }

  u16x8 rA[4], rW[4];
  {
    bool u1 = (0 < kSplit);
    const ushort* asrc = u1 ? A1 : A2;
    long ld = u1 ? lda1 : lda2;
    const long* g = u1 ? gA1 : gA2;
    #pragma unroll
    for (int c = 0; c < 4; c++){
      rA[c] = *(const u16x8*)(asrc + g[c]*ld + col8);
      rW[c] = *(const u16x8*)(Wt + gW[c]*ldw + col8);
    }
  }

  f32x4 acc[4][4];
  #pragma unroll
  for (int i = 0; i < 4; i++)
    #pragma unroll
    for (int j = 0; j < 4; j++) acc[i][j] = (f32x4){0.f,0.f,0.f,0.f};

  for (int k0 = 0; k0 < K; k0 += 64){
    #pragma unroll
    for (int c = 0; c < 4; c++){
      *(u16x8*)((char*)As + wbyte[c]) = rA[c];
      *(u16x8*)((char*)Ws + wbyte[c]) = rW[c];
    }
    __syncthreads();
    int kn = k0 + 64;
    if (kn < K){
      bool u1 = (kn < kSplit);
      const ushort* asrc = u1 ? A1 : A2;
      long ld = u1 ? lda1 : lda2;
      const long* g = u1 ? gA1 : gA2;
      long colb = u1 ? (long)kn : (long)(kn - kSplit);
      #pragma unroll
      for (int c = 0; c < 4; c++){
        rA[c] = *(const u16x8*)(asrc + g[c]*ld + colb + col8);
        rW[c] = *(const u16x8*)(Wt + gW[c]*ldw + kn + col8);
      }
    }
    #pragma unroll
    for (int h = 0; h < 2; h++){
      bf16x8 af[4], bw[4];
      #pragma unroll
      for (int i = 0; i < 4; i++){
        int row = wr*64 + i*16 + fr;
        int byo = row*128 + ((h*64 + kc*16) ^ ((row & 7) << 4));
        af[i] = *(const bf16x8*)((const char*)As + byo);
      }
      #pragma unroll
      for (int j = 0; j < 4; j++){
        int row = wc*64 + j*16 + fr;
        int byo = row*128 + ((h*64 + kc*16) ^ ((row & 7) << 4));
        bw[j] = *(const bf16x8*)((const char*)Ws + byo);
      }
      #pragma unroll
      for (int i = 0; i < 4; i++)
        #pragma unroll
        for (int j = 0; j < 4; j++)
          acc[i][j] = __builtin_amdgcn_mfma_f32_16x16x32_bf16(bw[j], af[i], acc[i][j], 0, 0, 0);
    }
    __syncthreads();
  }

  float alpha = 1.f;
  if (MODE == 4) alpha = 0.5f*expf(-mtl[(long)s*3 + mtlIdx]);
  int ccol = lane & 15, cr4 = (lane >> 4)*4;
  bool vecN = ((Nc & 3) == 0);
  float* Cf = (float*)Cv + (long)s*sC;
  ushort* Cb = (ushort*)Cv + (long)s*sC;
  #pragma unroll
  for (int i = 0; i < 4; i++){
    int gm = m0 + wr*64 + i*16 + ccol;
    if (gm >= M) continue;
    long rowoff = (long)gm*ldc;
    #pragma unroll
    for (int j = 0; j < 4; j++){
      int gn0 = n0 + wc*64 + j*16 + cr4;
      if (gn0 >= Nc) continue;
      f32x4 v = acc[i][j];
      if (MODE != 4 && bias){ f32x4 bv = *(const f32x4*)&bias[gn0]; v += bv; }
      if (MODE == 1){ v = (f32x4){fmaxf(v[0],0.f),fmaxf(v[1],0.f),fmaxf(v[2],0.f),fmaxf(v[3],0.f)}; }
      if (OBF){
        u16x4* cp = (u16x4*)&Cb[rowoff + gn0];
        if (MODE == 4){
          u16x4 o = *cp;
          *cp = (u16x4){f2b(b2f(o[0]) + alpha*v[0]), f2b(b2f(o[1]) + alpha*v[1]),
                        f2b(b2f(o[2]) + alpha*v[2]), f2b(b2f(o[3]) + alpha*v[3])};
        } else {
          *cp = (u16x4){f2b(v[0]), f2b(v[1]), f2b(v[2]), f2b(v[3])};
        }
      } else {
        if (vecN){
          f32x4* cp = (f32x4*)&Cf[rowoff + gn0];
          if (MODE == 4){ f32x4 o = *cp; *cp = o + alpha*v; }
          else *cp = v;
        } else {
          #pragma unroll
          for (int r = 0; r < 4; r++){
            int gn = gn0 + r; if (gn >= Nc) continue;
            if (MODE == 4) Cf[rowoff + gn] += alpha*v[r];
            else Cf[rowoff + gn] = v[r];
          }
        }
      }
    }
  }
}

// ================= 3x3 attention (bf16 in/out) =================
__global__ void attn_k(const ushort* __restrict__ qkv, ushort* __restrict__ o){
  int s = blockIdx.z, m = blockIdx.x, h = blockIdx.y;
  const ushort* base = qkv + (long)s*QKV_S + (long)m*3*1536 + (long)h*256;
  int t = threadIdx.x;
  float q[3], k[3], v[3];
  #pragma unroll
  for (int i = 0; i < 3; i++){
    q[i] = b2f(base[(long)i*1536 + t]);
    k[i] = b2f(base[(long)i*1536 + 512 + t]);
    v[i] = b2f(base[(long)i*1536 + 1024 + t]);
  }
  __shared__ float sm[4];
  __shared__ float att[9];
  #pragma unroll
  for (int i = 0; i < 3; i++)
    #pragma unroll
    for (int j = 0; j < 3; j++){
      float p = q[i]*k[j];
      for (int off = 32; off; off >>= 1) p += __shfl_down(p, off);
      __syncthreads();
      if ((t & 63) == 0) sm[t >> 6] = p;
      __syncthreads();
      if (t == 0) att[i*3 + j] = (sm[0]+sm[1]+sm[2]+sm[3]) * 0.0625f;
    }
  __syncthreads();
  if (t < 3){
    float a = att[t*3], b = att[t*3+1], c = att[t*3+2];
    float mx = fmaxf(a, fmaxf(b, c));
    a = expf(a-mx); b = expf(b-mx); c = expf(c-mx);
    float inv = 1.f/(a+b+c);
    att[t*3] = a*inv; att[t*3+1] = b*inv; att[t*3+2] = c*inv;
  }
  __syncthreads();
  ushort* ob = o + (long)s*Z_S + (long)m*3*512 + (long)h*256;
  #pragma unroll
  for (int i = 0; i < 3; i++)
    ob[(long)i*512 + t] = f2b(att[i*3]*v[0] + att[i*3+1]*v[1] + att[i*3+2]*v[2]);
}

// ================= z = LN(res + t), bf16 =================
__global__ void add_ln_k(ushort* __restrict__ zout, long sZ,
                         const ushort* __restrict__ res, long sR, int mapN, int mapOff,
                         const ushort* __restrict__ tb, long sT,
                         const float* __restrict__ w, const float* __restrict__ b, long wstr){
  int s = blockIdx.z; int r = blockIdx.x;
  int g = r;
  if (mapN > 0){ int tr = r / mapN; g = tr*NPT + mapOff + (r - tr*mapN); }
  const ushort* rr = res + (long)s*sR + (long)g*HH;
  const ushort* tr_ = tb + (long)s*sT + (long)r*HH;
  const float* wr = w + (long)s*wstr;
  const float* br = b + (long)s*wstr;
  int d0 = threadIdx.x, d1 = threadIdx.x + 256;
  float x0 = b2f(rr[d0]) + b2f(tr_[d0]), x1 = b2f(rr[d1]) + b2f(tr_[d1]);
  __shared__ float sm[4];
  float tsum = x0 + x1;
  for (int off = 32; off; off >>= 1) tsum += __shfl_down(tsum, off);
  if ((threadIdx.x & 63) == 0) sm[threadIdx.x >> 6] = tsum;
  __syncthreads();
  float mean = (sm[0]+sm[1]+sm[2]+sm[3]) * (1.f/512.f);
  float e0 = x0 - mean, e1 = x1 - mean;
  float vs = e0*e0 + e1*e1;
  __syncthreads();
  for (int off = 32; off; off >>= 1) vs += __shfl_down(vs, off);
  if ((threadIdx.x & 63) == 0) sm[threadIdx.x >> 6] = vs;
  __syncthreads();
  float var = (sm[0]+sm[1]+sm[2]+sm[3]) * (1.f/512.f);
  float inv = 1.f/sqrtf(var + 1e-5f);
  ushort* zr = zout + (long)s*sZ + (long)r*HH;
  zr[d0] = f2b(e0*inv*wr[d0] + br[d0]);
  zr[d1] = f2b(e1*inv*wr[d1] + br[d1]);
}

// ================= leaf LSTM cell =================
__global__ void leaf_k(const ushort* __restrict__ iou, const float* __restrict__ c0,
                       ushort* __restrict__ hbuf, float* __restrict__ cbuf){
  int s = blockIdx.z, p = blockIdx.x;
  int tree = p / 729, j = p - tree*729;
  long row = (long)(tree*NPT + 364 + j)*HH;
  const ushort* iour = iou + (long)s*QKV_S + (long)p*1536;
  const float* c0r = c0 + (long)s*H_S + row;
  for (int d = threadIdx.x; d < HH; d += 256){
    float cn = sigm(b2f(iour[d])) * tanhf(b2f(iour[1024 + d])) + c0r[d];
    float hn = sigm(b2f(iour[512 + d])) * tanhf(cn);
    hbuf[(long)s*H_S + row + d] = f2b(hn);
    cbuf[(long)s*H_S + row + d] = cn;
  }
}

// ================= internal-node combine =================
__global__ void combine_k(const ushort* __restrict__ wxiou, const ushort* __restrict__ z,
                          const float* __restrict__ bfv, const float* __restrict__ cbuf,
                          ushort* __restrict__ hbuf, float* __restrict__ cout,
                          int n, int st, int cs){
  int s = blockIdx.z, p = blockIdx.x;
  int tree = p / n, j = p - tree*n;
  const ushort* wr_ = wxiou + (long)s*WXI_S + (long)p*2048;
  const ushort* zr  = z + (long)s*Z_S + (long)p*1536;
  const float* bfr  = bfv + (long)s*HH;
  const float* cch  = cbuf + (long)s*H_S + (long)(tree*NPT + cs + 3*j)*HH;
  long orow = (long)s*H_S + (long)(tree*NPT + st + j)*HH;
  for (int d = threadIdx.x; d < HH; d += 256){
    float wv = b2f(wr_[d]) + bfr[d];
    float cpre = 0.f;
    #pragma unroll
    for (int ch = 0; ch < 3; ch++){
      float fg = sigm(wv + b2f(zr[ch*512 + d]));
      cpre += fg * cch[ch*512 + d];
    }
    float iv = b2f(wr_[512 + d]), ov = b2f(wr_[1024 + d]), uv = b2f(wr_[1536 + d]);
    float cn = sigm(iv)*tanhf(uv) + cpre;
    float hn = sigm(ov)*tanhf(cn);
    hbuf[orow + d] = f2b(hn);
    cout[orow + d] = cn;
  }
}

// launch helper
#define GEMM(MODE, OBF, A1, LDA1, SA1, A2, LDA2, SA2, KSPL, MAPN, MAPOFF, WT, LDW, SW, \
             BI, SB, CC, LDC, SC, M, NC, K)                                            \
  do { int nbx_ = ((NC)+127)/128, nby_ = ((M)+127)/128;                                \
    mgemm_k<MODE, OBF><<<dim3(nbx_*nby_, 1, SIDES), 256, 0, stream>>>(                 \
      A1, LDA1, SA1, A2, LDA2, SA2, KSPL, MAPN, MAPOFF, WT, LDW, SW, BI, SB,           \
      CC, LDC, SC, M, NC, K, nbx_, mtl, 0); } while(0)
#define GEMM4(OBF, A1, LDA1, SA1, WT, LDW, SW, CC, LDC, SC, M, NC, K, IDX)             \
  do { int nbx_ = ((NC)+127)/128, nby_ = ((M)+127)/128;                                \
    mgemm_k<4, OBF><<<dim3(nbx_*nby_, 1, SIDES), 256, 0, stream>>>(                    \
      A1, LDA1, SA1, A1, LDA1, SA1, K, 0, 0, WT, LDW, SW, (const float*)nullptr, 0L,   \
      CC, LDC, SC, M, NC, K, nbx_, mtl, IDX); } while(0)

extern "C" void kernel_launch(void* const* d_in, const int* in_sizes, int n_in,
                              void* d_out, int out_size, void* d_ws, size_t ws_size,
                              hipStream_t stream){
  (void)in_sizes; (void)n_in; (void)out_size; (void)ws_size;
  const int*   user_ids  = (const int*)d_in[0];
  const int*   feat_ids  = (const int*)d_in[1];
  const int*   time_ids  = (const int*)d_in[2];
  const int*   mask      = (const int*)d_in[3];
  const float* user_emb  = (const float*)d_in[6];
  const float* fuse_emb  = (const float*)d_in[7];
  const float* time_pe   = (const float*)d_in[8];
  const float* Wf        = (const float*)d_in[9];
  const float* bf        = (const float*)d_in[10];
  const float* Wiou      = (const float*)d_in[11];
  const float* Uiou      = (const float*)d_in[12];
  const float* biou      = (const float*)d_in[13];
  const float* attn_in_w = (const float*)d_in[14];
  const float* attn_in_b = (const float*)d_in[15];
  const float* attn_out_w= (const float*)d_in[16];
  const float* attn_out_b= (const float*)d_in[17];
  const float* ff1_w     = (const float*)d_in[18];
  const float* ff1_b     = (const float*)d_in[19];
  const float* ff2_w     = (const float*)d_in[20];
  const float* ff2_b     = (const float*)d_in[21];
  const float* ln1_w     = (const float*)d_in[22];
  const float* ln1_b     = (const float*)d_in[23];
  const float* ln2_w     = (const float*)d_in[24];
  const float* ln2_b     = (const float*)d_in[25];
  const float* dec_poi_w = (const float*)d_in[26];
  const float* dec_poi_b = (const float*)d_in[27];
  const float* dec_cat_w = (const float*)d_in[28];
  const float* dec_cat_b = (const float*)d_in[29];
  const float* dec_coo_w = (const float*)d_in[30];
  const float* dec_coo_b = (const float*)d_in[31];
  const float* cat2poi_w = (const float*)d_in[32];
  const float* cat2poi_b = (const float*)d_in[33];
  const float* coo2poi_w = (const float*)d_in[34];
  const float* coo2poi_b = (const float*)d_in[35];
  const float* mtl       = (const float*)d_in[36];
  const float* c0        = (const float*)d_in[37];

  float* out = (float*)d_out;

  // ---- ws layout (bf16 persistent: Hb, weights) ----
  ushort* wsu = (ushort*)d_ws;
  ushort* Hb    = wsu;                         // [2][NN*512]
  ushort* ainW  = Hb    + 2*H_S;               // [2][2][1536*512]
  ushort* aoutW = ainW  + (long)2*2*1536*512;  // [2][2][512*512]
  ushort* f1W   = aoutW + (long)2*2*512*512;
  ushort* f2W   = f1W   + (long)2*2*512*512;
  ushort* wcomb = f2W   + (long)2*2*512*512;   // [2][2048*1792]
  ushort* dcatW = wcomb + (long)2*2048*1792;   // [2][300*512]
  ushort* dcooW = dcatW + (long)2*300*512;     // [2][50*512]
  ushort* weffB = dcooW + (long)2*50*512;      // [2][5000*512]
  float*  bcomb = (float*)(weffB + (long)2*WEFF_S);  // [2][2048]
  float*  beff  = bcomb + 2*2048;              // [2][5000]

  // ---- out-scratch (side-1 poi region; dead before final GEMM writes it) ----
  float*  Cb   = out + OUT_S;                  // [2][NN*512] f32
  ushort* osu  = (ushort*)(Cb + 2*H_S);
  ushort* QKV  = osu;                          // [2][TOKMAX*1536]
  ushort* Zb   = QKV  + 2*QKV_S;               // [2][TOKMAX*512]
  ushort* TMP  = Zb   + 2*Z_S;
  ushort* WXI  = TMP  + 2*Z_S;                 // [2][PARMAX*2048]
  ushort* Xb   = WXI  + 2*WXI_S;               // [2][NN*256]
  ushort* c2pB = Xb   + 2*X_S;                 // [2][5000*320]
  ushort* o2pB = c2pB + (long)2*5000*320;      // [2][5000*64]
  ushort* dctT = o2pB + (long)2*5000*64;       // [2][512*320]
  ushort* dcoT = dctT + (long)2*512*320;       // [2][512*64]

  // ---- preconvert ----
  {
    long n0 = (long)2*2*1536*512, n1 = (long)2*2*512*512, n2 = n1, n3 = n1;
    long n4 = (long)2*300*512, n5 = (long)2*50*512;
    long tot4 = (n0+n1+n2+n3+n4+n5)/4;
    mcvt_k<<<dim3((tot4+255)/256), 256, 0, stream>>>(
        ainW, attn_in_w, n0, aoutW, attn_out_w, n1, f1W, ff1_w, n2,
        f2W, ff2_w, n3, dcatW, dec_cat_w, n4, dcooW, dec_coo_w, n5);
  }
  wcomb_k<<<dim3(2048, 7, SIDES), 256, 0, stream>>>(wcomb, Wf, Wiou, Uiou);
  bcomb_k<<<dim3(8, 1, SIDES), 256, 0, stream>>>(bcomb, biou);
  padcvt_k<<<dim3(5000, 2, SIDES), 256, 0, stream>>>(c2pB, cat2poi_w, 5000, 300, 320);
  padcvt_k<<<dim3(5000, 1, SIDES), 256, 0, stream>>>(o2pB, coo2poi_w, 5000, 50, 64);
  tpcvt_k<<<dim3(512, 1, SIDES), 320, 0, stream>>>(dctT, dec_cat_w, 300, 320);
  tpcvt_k<<<dim3(512, 1, SIDES), 64, 0, stream>>>(dcoT, dec_coo_w, 50, 64);
  weffinit_k<<<dim3(2500, 1, SIDES), 256, 0, stream>>>(weffB, dec_poi_w, mtl);
  beff_k<<<dim3(20, 1, SIDES), 256, 0, stream>>>(beff, dec_poi_b, dec_cat_b,
       cat2poi_w, cat2poi_b, dec_coo_b, coo2poi_w, coo2poi_b, mtl);

  // ---- embeddings ----
  embed_k<<<dim3(NN, 1, SIDES), 256, 0, stream>>>(user_ids, feat_ids, time_ids, mask,
                                                  user_emb, fuse_emb, time_pe, Xb);

  // ---- leaves: iou0 = x @ Wiou^T (rows of wcomb 512..2047, K=256), no bias ----
  GEMM(0, true, Xb, 256L, X_S, Xb, 256L, X_S, 256, 729, 364,
       wcomb + (long)512*1792, 1792L, (long)2048*1792,
       (const float*)nullptr, 0L, QKV, 1536L, QKV_S, 5832, 1536, 256);
  leaf_k<<<dim3(5832, 1, SIDES), 256, 0, stream>>>(QKV, c0, Hb, Cb);

  const int p3[7]   = {1,3,9,27,81,243,729};
  const int offs[7] = {0,1,4,13,40,121,364};

  // ---- internal levels ----
  for (int l = 5; l >= 0; l--){
    int n = p3[l], st = offs[l], cs = offs[l+1];
    int P = NTREE*n, T = 3*P;
    for (int L = 0; L < LAYERS; L++){
      const ushort* zin = (L == 0) ? Hb : Zb;
      long zld = 512, zs = (L == 0) ? H_S : Z_S;
      int mN = (L == 0) ? 3*n : 0, mO = (L == 0) ? cs : 0;
      GEMM(0, true, zin, zld, zs, zin, zld, zs, 512, mN, mO,
           ainW + (long)L*1536*512, 512L, (long)2*1536*512,
           attn_in_b + (long)L*1536, (long)LAYERS*1536, QKV, 1536L, QKV_S, T, 1536, 512);
      attn_k<<<dim3(P, 2, SIDES), 256, 0, stream>>>(QKV, TMP);
      GEMM(0, true, TMP, 512L, Z_S, TMP, 512L, Z_S, 512, 0, 0,
           aoutW + (long)L*512*512, 512L, (long)2*512*512,
           attn_out_b + (long)L*512, (long)LAYERS*512, QKV, 512L, QKV_S, T, 512, 512);
      add_ln_k<<<dim3(T, 1, SIDES), 256, 0, stream>>>(Zb, Z_S, zin, zs, mN, mO,
           QKV, QKV_S, ln1_w + (long)L*512, ln1_b + (long)L*512, (long)LAYERS*512);
      GEMM(1, true, Zb, 512L, Z_S, Zb, 512L, Z_S, 512, 0, 0,
           f1W + (long)L*512*512, 512L, (long)2*512*512,
           ff1_b + (long)L*512, (long)LAYERS*512, TMP, 512L, Z_S, T, 512, 512);
      GEMM(0, true, TMP, 512L, Z_S, TMP, 512L, Z_S, 512, 0, 0,
           f2W + (long)L*512*512, 512L, (long)2*512*512,
           ff2_b + (long)L*512, (long)LAYERS*512, QKV, 512L, QKV_S, T, 512, 512);
      add_ln_k<<<dim3(T, 1, SIDES), 256, 0, stream>>>(Zb, Z_S, Zb, Z_S, 0, 0,
           QKV, QKV_S, ln2_w + (long)L*512, ln2_b + (long)L*512, (long)LAYERS*512);
    }
    // [wx | iou] = [x | z] @ [Wf|0 ; Wiou|Uiou]^T + [0|biou]
    GEMM(0, true, Xb, 256L, X_S, Zb, 1536L, Z_S, 256, n, st,
         wcomb, 1792L, (long)2048*1792, bcomb, 2048L, WXI, 2048L, WXI_S, P, 2048, 1792);
    combine_k<<<dim3(P, 1, SIDES), 256, 0, stream>>>(WXI, Zb, bf, Cb, Hb, Cb, n, st, cs);
  }

  // ---- cat/coo decoders (per-side W stride = NCAT*512 / NCOO*512!) ----
  GEMM(0, false, Hb, 512L, H_S, Hb, 512L, H_S, 512, 0, 0,
       dcatW, 512L, (long)NCAT*512, dec_cat_b, (long)NCAT,
       out + CAT_OFF, (long)NCAT, OUT_S, NN, NCAT, 512);
  GEMM(0, false, Hb, 512L, H_S, Hb, 512L, H_S, 512, 0, 0,
       dcooW, 512L, (long)NCOO*512, dec_coo_b, (long)NCOO,
       out + COO_OFF, (long)NCOO, OUT_S, NN, NCOO, 512);

  // ---- Weff += a1*cat2poi@dec_cat^T, += a2*coo2poi@dec_coo^T (bf16 RMW) ----
  GEMM4(true, c2pB, 320L, (long)5000*320, dctT, 320L, (long)512*320,
        weffB, 512L, WEFF_S, 5000, 512, 320, 1);
  GEMM4(true, o2pB, 64L, (long)5000*64, dcoT, 64L, (long)512*64,
        weffB, 512L, WEFF_S, 5000, 512, 64, 2);

  // ---- fused poi decoder ----
  GEMM(0, false, Hb, 512L, H_S, Hb, 512L, H_S, 512, 0, 0,
       weffB, 512L, WEFF_S, beff, (long)NPOI,
       out, (long)NPOI, OUT_S, NN, NPOI, 512);
}

// Round 7
// 1651.087 us; speedup vs baseline: 6.6609x; 1.0010x over previous
//
#include <hip/hip_runtime.h>
#include <math.h>

#define SIDES 2
#define LAYERS 2
#define NTREE 8
#define NPT 1093
#define NN (NTREE*NPT)        // 8744
#define EE 256
#define HH 512
#define NUSERS 2000
#define NPOI 5000
#define NCAT 300
#define NCOO 50
#define FUSEN 5350
#define TMAXN 600
#define TOKMAX 5832           // 8*729
#define PARMAX 1944           // 8*243

constexpr long OUT_S   = 46780400L;   // per-side output block (floats)
constexpr long CAT_OFF = 43720000L;
constexpr long COO_OFF = 46343200L;

// element strides per side
constexpr long H_S    = (long)NN*HH;        // 4,476,928
constexpr long X_S    = (long)NN*EE;        // 2,238,464
constexpr long Z_S    = (long)TOKMAX*HH;    // 2,985,984
constexpr long QKV_S  = (long)TOKMAX*3*HH;  // 8,957,952
constexpr long WXI_S  = (long)PARMAX*2048;  // 3,981,312
constexpr long WEFF_S = (long)NPOI*HH;      // 2,560,000

typedef __attribute__((ext_vector_type(8))) short  bf16x8;
typedef __attribute__((ext_vector_type(8))) ushort u16x8;
typedef __attribute__((ext_vector_type(4))) ushort u16x4;
typedef __attribute__((ext_vector_type(4))) float  f32x4;

__device__ __forceinline__ float sigm(float x){ return 1.f/(1.f+expf(-x)); }
__device__ __forceinline__ ushort f2b(float f){
  union { float f; unsigned u; } v; v.f = f;
  return (ushort)((v.u + 0x7fffu + ((v.u >> 16) & 1u)) >> 16);
}
__device__ __forceinline__ float b2f(ushort u){
  union { unsigned u; float f; } v; v.u = (unsigned)u << 16; return v.f;
}

// ================= preconvert kernels =================
__global__ void mcvt_k(ushort* d0, const float* s0, long n0,
                       ushort* d1, const float* s1, long n1,
                       ushort* d2, const float* s2, long n2,
                       ushort* d3, const float* s3, long n3,
                       ushort* d4, const float* s4, long n4,
                       ushort* d5, const float* s5, long n5){
  long g4 = (long)blockIdx.x*blockDim.x + threadIdx.x;
  long i = g4*4;
  ushort* d; const float* s; long off;
  if      (i < n0){ d=d0; s=s0; off=i; }
  else if ((i-=n0) < n1){ d=d1; s=s1; off=i; }
  else if ((i-=n1) < n2){ d=d2; s=s2; off=i; }
  else if ((i-=n2) < n3){ d=d3; s=s3; off=i; }
  else if ((i-=n3) < n4){ d=d4; s=s4; off=i; }
  else if ((i-=n4) < n5){ d=d5; s=s5; off=i; }
  else return;
  f32x4 v = *(const f32x4*)(s + off);
  *(u16x4*)(d + off) = (u16x4){f2b(v[0]), f2b(v[1]), f2b(v[2]), f2b(v[3])};
}

// W_comb[2048][1792]: rows 0-511 = [Wf | 0], rows 512-2047 = [Wiou | Uiou]
__global__ void wcomb_k(ushort* __restrict__ dst, const float* __restrict__ Wf,
                        const float* __restrict__ Wiou, const float* __restrict__ Uiou){
  int s = blockIdx.z; int row = blockIdx.x; int col = blockIdx.y*256 + threadIdx.x;
  float v;
  if (row < 512) v = (col < 256) ? Wf[((long)s*512 + row)*256 + col] : 0.f;
  else {
    int r = row - 512;
    v = (col < 256) ? Wiou[((long)s*1536 + r)*256 + col]
                    : Uiou[((long)s*1536 + r)*1536 + (col-256)];
  }
  dst[(long)s*2048*1792 + (long)row*1792 + col] = f2b(v);
}

__global__ void bcomb_k(float* __restrict__ dst, const float* __restrict__ biou){
  int s = blockIdx.z; int c = blockIdx.x*256 + threadIdx.x;
  dst[(long)s*2048 + c] = (c < 512) ? 0.f : biou[(long)s*1536 + (c-512)];
}

// pad+convert: dst[rows][dcols] <- src[rows][scols] (zero pad)
__global__ void padcvt_k(ushort* __restrict__ dst, const float* __restrict__ src,
                         int rows, int scols, int dcols){
  int s = blockIdx.z; int r = blockIdx.x; int c = blockIdx.y*256 + threadIdx.x;
  if (c >= dcols) return;
  float v = (c < scols) ? src[((long)s*rows + r)*scols + c] : 0.f;
  dst[((long)s*rows + r)*dcols + c] = f2b(v);
}

// transpose+pad+convert: dst[512][dcols] <- src[srows][512]^T
__global__ void tpcvt_k(ushort* __restrict__ dst, const float* __restrict__ src,
                        int srows, int dcols){
  int s = blockIdx.z; int h = blockIdx.x; int c = threadIdx.x;
  float v = (c < srows) ? src[((long)s*srows + c)*512 + h] : 0.f;
  dst[((long)s*512 + h)*dcols + c] = f2b(v);
}

// Weff_bf init = a0 * dec_poi_w
__global__ void weffinit_k(ushort* __restrict__ dst, const float* __restrict__ poi_w,
                           const float* __restrict__ mtl){
  int s = blockIdx.z;
  long i = ((long)blockIdx.x*blockDim.x + threadIdx.x)*4;
  float a0 = 0.5f*expf(-mtl[(long)s*3]);
  f32x4 v = *(const f32x4*)(poi_w + (long)s*WEFF_S + i);
  *(u16x4*)(dst + (long)s*WEFF_S + i) =
      (u16x4){f2b(a0*v[0]), f2b(a0*v[1]), f2b(a0*v[2]), f2b(a0*v[3])};
}

__global__ void beff_k(float* __restrict__ beff, const float* __restrict__ poi_b,
                       const float* __restrict__ cat_b, const float* __restrict__ c2p_w,
                       const float* __restrict__ c2p_b, const float* __restrict__ coo_b,
                       const float* __restrict__ o2p_w, const float* __restrict__ o2p_b,
                       const float* __restrict__ mtl){
  int s = blockIdx.z;
  int n = blockIdx.x*blockDim.x + threadIdx.x;
  if (n >= NPOI) return;
  const float* mt = mtl + (long)s*3;
  float a0 = 0.5f*expf(-mt[0]), a1 = 0.5f*expf(-mt[1]), a2 = 0.5f*expf(-mt[2]);
  float acc1 = 0.f, acc2 = 0.f;
  for (int c = 0; c < NCAT; c++)
    acc1 += cat_b[(long)s*NCAT + c] * c2p_w[((long)s*NPOI + n)*NCAT + c];
  for (int c = 0; c < NCOO; c++)
    acc2 += coo_b[(long)s*NCOO + c] * o2p_w[((long)s*NPOI + n)*NCOO + c];
  beff[(long)s*NPOI + n] = a0*poi_b[(long)s*NPOI + n]
      + a1*(acc1 + c2p_b[(long)s*NPOI + n]) + a2*(acc2 + o2p_b[(long)s*NPOI + n])
      + mt[0] + mt[1] + mt[2];
}

// ================= embedding (bf16 out) =================
__global__ void embed_k(const int* __restrict__ uid, const int* __restrict__ fid,
                        const int* __restrict__ tid, const int* __restrict__ mask,
                        const float* __restrict__ uemb, const float* __restrict__ femb,
                        const float* __restrict__ tpe, ushort* __restrict__ X){
  int s = blockIdx.z; long i = blockIdx.x; int d = threadIdx.x;
  int m = mask[(long)s*NN + i];
  int u = uid[(long)s*NN + i]*m, f = fid[(long)s*NN + i]*m, t = tid[(long)s*NN + i]*m;
  float e = (d < 128) ? uemb[((long)s*NUSERS + u)*128 + d]
                      : femb[((long)s*FUSEN + f)*128 + (d-128)];
  e += 0.5f * tpe[((long)s*TMAXN + t)*256 + d];
  X[(long)s*X_S + i*EE + d] = f2b(e * (float)m);
}

// ================= bf16 MFMA GEMM =================
// C = epilogue(A @ W^T + bias); A,W bf16; C f32 or bf16.
// A dual-source: k<kSplit from A1 (optionally tree-row-mapped), else A2 (dense rows).
// MODE 0: store(+bias); 1: relu; 4: C += alpha*acc  [alpha = 0.5*exp(-mtl[idx])]
template<int MODE, bool OBF>
__global__ void __launch_bounds__(256)
mgemm_k(const ushort* __restrict__ A1, long lda1, long sA1,
        const ushort* __restrict__ A2, long lda2, long sA2,
        int kSplit, int mapN, int mapOff,
        const ushort* __restrict__ Wt, long ldw, long sW,
        const float* __restrict__ bias, long sB,
        void* __restrict__ Cv, long ldc, long sC,
        int M, int Nc, int K, int nbx,
        const float* __restrict__ mtl, int mtlIdx){
  int s = blockIdx.z;
  A1 += (long)s*sA1; A2 += (long)s*sA2; Wt += (long)s*sW;
  if (bias) bias += (long)s*sB;

  // bijective xcd swizzle (m204)
  int flat = blockIdx.x, nwg = gridDim.x;
  int xcd = flat & 7, q = nwg >> 3, r8 = nwg & 7;
  int nf = (xcd < r8 ? xcd*(q+1) : r8*(q+1) + (xcd - r8)*q) + (flat >> 3);
  int bx = nf % nbx, by = nf / nbx;
  int m0 = by*128, n0 = bx*128;

  __shared__ ushort As[128*64];
  __shared__ ushort Ws[128*64];

  int tid = threadIdx.x;
  int lane = tid & 63, wave = tid >> 6;
  int wr = wave >> 1, wc = wave & 1;
  int fr = lane & 15, kc = lane >> 4;

  // staging: chunk c covers row = (tid>>3)+32c, 8-elem col group c16 = tid&7
  int baseRow = tid >> 3;
  int c16 = tid & 7;
  int col8 = c16*8;
  int swz = (baseRow & 7) << 4;

  long gA1[4], gA2[4], gW[4];
  int wbyte[4];
  #pragma unroll
  for (int c = 0; c < 4; c++){
    int row = baseRow + c*32;
    int ra = m0 + row; if (ra > M-1) ra = M-1;
    gA2[c] = ra;                                   // dense (A2)
    if (mapN > 0){ int tr = ra / mapN; gA1[c] = (long)(tr*NPT + mapOff + (ra - tr*mapN)); }
    else gA1[c] = ra;                              // mapped (A1)
    int rw = n0 + row; if (rw > Nc-1) rw = Nc-1;
    gW[c] = rw;
    wbyte[c] = row*128 + ((c16*16) ^ swz);
  }

  u16x8 rA[4], rW[4];
  {
    bool u1 = (0 < kSplit);
    const ushort* asrc = u1 ? A1 : A2;
    long ld = u1 ? lda1 : lda2;
    const long* g = u1 ? gA1 : gA2;
    #pragma unroll
    for (int c = 0; c < 4; c++){
      rA[c] = *(const u16x8*)(asrc + g[c]*ld + col8);
      rW[c] = *(const u16x8*)(Wt + gW[c]*ldw + col8);
    }
  }

  f32x4 acc[4][4];
  #pragma unroll
  for (int i = 0; i < 4; i++)
    #pragma unroll
    for (int j = 0; j < 4; j++) acc[i][j] = (f32x4){0.f,0.f,0.f,0.f};

  for (int k0 = 0; k0 < K; k0 += 64){
    #pragma unroll
    for (int c = 0; c < 4; c++){
      *(u16x8*)((char*)As + wbyte[c]) = rA[c];
      *(u16x8*)((char*)Ws + wbyte[c]) = rW[c];
    }
    __syncthreads();
    int kn = k0 + 64;
    if (kn < K){
      bool u1 = (kn < kSplit);
      const ushort* asrc = u1 ? A1 : A2;
      long ld = u1 ? lda1 : lda2;
      const long* g = u1 ? gA1 : gA2;
      long colb = u1 ? (long)kn : (long)(kn - kSplit);
      #pragma unroll
      for (int c = 0; c < 4; c++){
        rA[c] = *(const u16x8*)(asrc + g[c]*ld + colb + col8);
        rW[c] = *(const u16x8*)(Wt + gW[c]*ldw + kn + col8);
      }
    }
    #pragma unroll
    for (int h = 0; h < 2; h++){
      bf16x8 af[4], bw[4];
      #pragma unroll
      for (int i = 0; i < 4; i++){
        int row = wr*64 + i*16 + fr;
        int byo = row*128 + ((h*64 + kc*16) ^ ((row & 7) << 4));
        af[i] = *(const bf16x8*)((const char*)As + byo);
      }
      #pragma unroll
      for (int j = 0; j < 4; j++){
        int row = wc*64 + j*16 + fr;
        int byo = row*128 + ((h*64 + kc*16) ^ ((row & 7) << 4));
        bw[j] = *(const bf16x8*)((const char*)Ws + byo);
      }
      #pragma unroll
      for (int i = 0; i < 4; i++)
        #pragma unroll
        for (int j = 0; j < 4; j++)
          acc[i][j] = __builtin_amdgcn_mfma_f32_16x16x32_bf16(bw[j], af[i], acc[i][j], 0, 0, 0);
    }
    __syncthreads();
  }

  float alpha = 1.f;
  if (MODE == 4) alpha = 0.5f*expf(-mtl[(long)s*3 + mtlIdx]);
  int ccol = lane & 15, cr4 = (lane >> 4)*4;
  bool vecN = ((Nc & 3) == 0);
  float* Cf = (float*)Cv + (long)s*sC;
  ushort* Cb = (ushort*)Cv + (long)s*sC;
  #pragma unroll
  for (int i = 0; i < 4; i++){
    int gm = m0 + wr*64 + i*16 + ccol;
    if (gm >= M) continue;
    long rowoff = (long)gm*ldc;
    #pragma unroll
    for (int j = 0; j < 4; j++){
      int gn0 = n0 + wc*64 + j*16 + cr4;
      if (gn0 >= Nc) continue;
      f32x4 v = acc[i][j];
      if (MODE != 4 && bias){ f32x4 bv = *(const f32x4*)&bias[gn0]; v += bv; }
      if (MODE == 1){ v = (f32x4){fmaxf(v[0],0.f),fmaxf(v[1],0.f),fmaxf(v[2],0.f),fmaxf(v[3],0.f)}; }
      if (OBF){
        u16x4* cp = (u16x4*)&Cb[rowoff + gn0];
        if (MODE == 4){
          u16x4 o = *cp;
          *cp = (u16x4){f2b(b2f(o[0]) + alpha*v[0]), f2b(b2f(o[1]) + alpha*v[1]),
                        f2b(b2f(o[2]) + alpha*v[2]), f2b(b2f(o[3]) + alpha*v[3])};
        } else {
          *cp = (u16x4){f2b(v[0]), f2b(v[1]), f2b(v[2]), f2b(v[3])};
        }
      } else {
        if (vecN){
          f32x4* cp = (f32x4*)&Cf[rowoff + gn0];
          if (MODE == 4){ f32x4 o = *cp; *cp = o + alpha*v; }
          else *cp = v;
        } else {
          #pragma unroll
          for (int r = 0; r < 4; r++){
            int gn = gn0 + r; if (gn >= Nc) continue;
            if (MODE == 4) Cf[rowoff + gn] += alpha*v[r];
            else Cf[rowoff + gn] = v[r];
          }
        }
      }
    }
  }
}

// ================= 3x3 attention (bf16 in/out) =================
__global__ void attn_k(const ushort* __restrict__ qkv, ushort* __restrict__ o){
  int s = blockIdx.z, m = blockIdx.x, h = blockIdx.y;
  const ushort* base = qkv + (long)s*QKV_S + (long)m*3*1536 + (long)h*256;
  int t = threadIdx.x;
  float q[3], k[3], v[3];
  #pragma unroll
  for (int i = 0; i < 3; i++){
    q[i] = b2f(base[(long)i*1536 + t]);
    k[i] = b2f(base[(long)i*1536 + 512 + t]);
    v[i] = b2f(base[(long)i*1536 + 1024 + t]);
  }
  __shared__ float sm[4];
  __shared__ float att[9];
  #pragma unroll
  for (int i = 0; i < 3; i++)
    #pragma unroll
    for (int j = 0; j < 3; j++){
      float p = q[i]*k[j];
      for (int off = 32; off; off >>= 1) p += __shfl_down(p, off);
      __syncthreads();
      if ((t & 63) == 0) sm[t >> 6] = p;
      __syncthreads();
      if (t == 0) att[i*3 + j] = (sm[0]+sm[1]+sm[2]+sm[3]) * 0.0625f;
    }
  __syncthreads();
  if (t < 3){
    float a = att[t*3], b = att[t*3+1], c = att[t*3+2];
    float mx = fmaxf(a, fmaxf(b, c));
    a = expf(a-mx); b = expf(b-mx); c = expf(c-mx);
    float inv = 1.f/(a+b+c);
    att[t*3] = a*inv; att[t*3+1] = b*inv; att[t*3+2] = c*inv;
  }
  __syncthreads();
  ushort* ob = o + (long)s*Z_S + (long)m*3*512 + (long)h*256;
  #pragma unroll
  for (int i = 0; i < 3; i++)
    ob[(long)i*512 + t] = f2b(att[i*3]*v[0] + att[i*3+1]*v[1] + att[i*3+2]*v[2]);
}

// ================= z = LN(res + t), bf16 =================
__global__ void add_ln_k(ushort* __restrict__ zout, long sZ,
                         const ushort* __restrict__ res, long sR, int mapN, int mapOff,
                         const ushort* __restrict__ tb, long sT,
                         const float* __restrict__ w, const float* __restrict__ b, long wstr){
  int s = blockIdx.z; int r = blockIdx.x;
  int g = r;
  if (mapN > 0){ int tr = r / mapN; g = tr*NPT + mapOff + (r - tr*mapN); }
  const ushort* rr = res + (long)s*sR + (long)g*HH;
  const ushort* tr_ = tb + (long)s*sT + (long)r*HH;
  const float* wr = w + (long)s*wstr;
  const float* br = b + (long)s*wstr;
  int d0 = threadIdx.x, d1 = threadIdx.x + 256;
  float x0 = b2f(rr[d0]) + b2f(tr_[d0]), x1 = b2f(rr[d1]) + b2f(tr_[d1]);
  __shared__ float sm[4];
  float tsum = x0 + x1;
  for (int off = 32; off; off >>= 1) tsum += __shfl_down(tsum, off);
  if ((threadIdx.x & 63) == 0) sm[threadIdx.x >> 6] = tsum;
  __syncthreads();
  float mean = (sm[0]+sm[1]+sm[2]+sm[3]) * (1.f/512.f);
  float e0 = x0 - mean, e1 = x1 - mean;
  float vs = e0*e0 + e1*e1;
  __syncthreads();
  for (int off = 32; off; off >>= 1) vs += __shfl_down(vs, off);
  if ((threadIdx.x & 63) == 0) sm[threadIdx.x >> 6] = vs;
  __syncthreads();
  float var = (sm[0]+sm[1]+sm[2]+sm[3]) * (1.f/512.f);
  float inv = 1.f/sqrtf(var + 1e-5f);
  ushort* zr = zout + (long)s*sZ + (long)r*HH;
  zr[d0] = f2b(e0*inv*wr[d0] + br[d0]);
  zr[d1] = f2b(e1*inv*wr[d1] + br[d1]);
}

// ================= leaf LSTM cell =================
__global__ void leaf_k(const ushort* __restrict__ iou, const float* __restrict__ c0,
                       ushort* __restrict__ hbuf, float* __restrict__ cbuf){
  int s = blockIdx.z, p = blockIdx.x;
  int tree = p / 729, j = p - tree*729;
  long row = (long)(tree*NPT + 364 + j)*HH;
  const ushort* iour = iou + (long)s*QKV_S + (long)p*1536;
  const float* c0r = c0 + (long)s*H_S + row;
  for (int d = threadIdx.x; d < HH; d += 256){
    float cn = sigm(b2f(iour[d])) * tanhf(b2f(iour[1024 + d])) + c0r[d];
    float hn = sigm(b2f(iour[512 + d])) * tanhf(cn);
    hbuf[(long)s*H_S + row + d] = f2b(hn);
    cbuf[(long)s*H_S + row + d] = cn;
  }
}

// ================= internal-node combine =================
__global__ void combine_k(const ushort* __restrict__ wxiou, const ushort* __restrict__ z,
                          const float* __restrict__ bfv, const float* __restrict__ cbuf,
                          ushort* __restrict__ hbuf, float* __restrict__ cout,
                          int n, int st, int cs){
  int s = blockIdx.z, p = blockIdx.x;
  int tree = p / n, j = p - tree*n;
  const ushort* wr_ = wxiou + (long)s*WXI_S + (long)p*2048;
  const ushort* zr  = z + (long)s*Z_S + (long)p*1536;
  const float* bfr  = bfv + (long)s*HH;
  const float* cch  = cbuf + (long)s*H_S + (long)(tree*NPT + cs + 3*j)*HH;
  long orow = (long)s*H_S + (long)(tree*NPT + st + j)*HH;
  for (int d = threadIdx.x; d < HH; d += 256){
    float wv = b2f(wr_[d]) + bfr[d];
    float cpre = 0.f;
    #pragma unroll
    for (int ch = 0; ch < 3; ch++){
      float fg = sigm(wv + b2f(zr[ch*512 + d]));
      cpre += fg * cch[ch*512 + d];
    }
    float iv = b2f(wr_[512 + d]), ov = b2f(wr_[1024 + d]), uv = b2f(wr_[1536 + d]);
    float cn = sigm(iv)*tanhf(uv) + cpre;
    float hn = sigm(ov)*tanhf(cn);
    hbuf[orow + d] = f2b(hn);
    cout[orow + d] = cn;
  }
}

// launch helper
#define GEMM(MODE, OBF, A1, LDA1, SA1, A2, LDA2, SA2, KSPL, MAPN, MAPOFF, WT, LDW, SW, \
             BI, SB, CC, LDC, SC, M, NC, K)                                            \
  do { int nbx_ = ((NC)+127)/128, nby_ = ((M)+127)/128;                                \
    mgemm_k<MODE, OBF><<<dim3(nbx_*nby_, 1, SIDES), 256, 0, stream>>>(                 \
      A1, LDA1, SA1, A2, LDA2, SA2, KSPL, MAPN, MAPOFF, WT, LDW, SW, BI, SB,           \
      CC, LDC, SC, M, NC, K, nbx_, mtl, 0); } while(0)
#define GEMM4(OBF, A1, LDA1, SA1, WT, LDW, SW, CC, LDC, SC, M, NC, K, IDX)             \
  do { int nbx_ = ((NC)+127)/128, nby_ = ((M)+127)/128;                                \
    mgemm_k<4, OBF><<<dim3(nbx_*nby_, 1, SIDES), 256, 0, stream>>>(                    \
      A1, LDA1, SA1, A1, LDA1, SA1, K, 0, 0, WT, LDW, SW, (const float*)nullptr, 0L,   \
      CC, LDC, SC, M, NC, K, nbx_, mtl, IDX); } while(0)

extern "C" void kernel_launch(void* const* d_in, const int* in_sizes, int n_in,
                              void* d_out, int out_size, void* d_ws, size_t ws_size,
                              hipStream_t stream){
  (void)in_sizes; (void)n_in; (void)out_size; (void)ws_size;
  const int*   user_ids  = (const int*)d_in[0];
  const int*   feat_ids  = (const int*)d_in[1];
  const int*   time_ids  = (const int*)d_in[2];
  const int*   mask      = (const int*)d_in[3];
  const float* user_emb  = (const float*)d_in[6];
  const float* fuse_emb  = (const float*)d_in[7];
  const float* time_pe   = (const float*)d_in[8];
  const float* Wf        = (const float*)d_in[9];
  const float* bf        = (const float*)d_in[10];
  const float* Wiou      = (const float*)d_in[11];
  const float* Uiou      = (const float*)d_in[12];
  const float* biou      = (const float*)d_in[13];
  const float* attn_in_w = (const float*)d_in[14];
  const float* attn_in_b = (const float*)d_in[15];
  const float* attn_out_w= (const float*)d_in[16];
  const float* attn_out_b= (const float*)d_in[17];
  const float* ff1_w     = (const float*)d_in[18];
  const float* ff1_b     = (const float*)d_in[19];
  const float* ff2_w     = (const float*)d_in[20];
  const float* ff2_b     = (const float*)d_in[21];
  const float* ln1_w     = (const float*)d_in[22];
  const float* ln1_b     = (const float*)d_in[23];
  const float* ln2_w     = (const float*)d_in[24];
  const float* ln2_b     = (const float*)d_in[25];
  const float* dec_poi_w = (const float*)d_in[26];
  const float* dec_poi_b = (const float*)d_in[27];
  const float* dec_cat_w = (const float*)d_in[28];
  const float* dec_cat_b = (const float*)d_in[29];
  const float* dec_coo_w = (const float*)d_in[30];
  const float* dec_coo_b = (const float*)d_in[31];
  const float* cat2poi_w = (const float*)d_in[32];
  const float* cat2poi_b = (const float*)d_in[33];
  const float* coo2poi_w = (const float*)d_in[34];
  const float* coo2poi_b = (const float*)d_in[35];
  const float* mtl       = (const float*)d_in[36];
  const float* c0        = (const float*)d_in[37];

  float* out = (float*)d_out;

  // ---- ws layout (bf16 persistent: Hb, weights) ----
  ushort* wsu = (ushort*)d_ws;
  ushort* Hb    = wsu;                         // [2][NN*512]
  ushort* ainW  = Hb    + 2*H_S;               // [2][2][1536*512]
  ushort* aoutW = ainW  + (long)2*2*1536*512;  // [2][2][512*512]
  ushort* f1W   = aoutW + (long)2*2*512*512;
  ushort* f2W   = f1W   + (long)2*2*512*512;
  ushort* wcomb = f2W   + (long)2*2*512*512;   // [2][2048*1792]
  ushort* dcatW = wcomb + (long)2*2048*1792;   // [2][300*512]
  ushort* dcooW = dcatW + (long)2*300*512;     // [2][50*512]
  ushort* weffB = dcooW + (long)2*50*512;      // [2][5000*512]
  float*  bcomb = (float*)(weffB + (long)2*WEFF_S);  // [2][2048]
  float*  beff  = bcomb + 2*2048;              // [2][5000]

  // ---- out-scratch (side-1 poi region; dead before final GEMM writes it) ----
  float*  Cb   = out + OUT_S;                  // [2][NN*512] f32
  ushort* osu  = (ushort*)(Cb + 2*H_S);
  ushort* QKV  = osu;                          // [2][TOKMAX*1536]
  ushort* Zb   = QKV  + 2*QKV_S;               // [2][TOKMAX*512]
  ushort* TMP  = Zb   + 2*Z_S;
  ushort* WXI  = TMP  + 2*Z_S;                 // [2][PARMAX*2048]
  ushort* Xb   = WXI  + 2*WXI_S;               // [2][NN*256]
  ushort* c2pB = Xb   + 2*X_S;                 // [2][5000*320]
  ushort* o2pB = c2pB + (long)2*5000*320;      // [2][5000*64]
  ushort* dctT = o2pB + (long)2*5000*64;       // [2][512*320]
  ushort* dcoT = dctT + (long)2*512*320;       // [2][512*64]

  // ---- preconvert ----
  {
    long n0 = (long)2*2*1536*512, n1 = (long)2*2*512*512, n2 = n1, n3 = n1;
    long n4 = (long)2*300*512, n5 = (long)2*50*512;
    long tot4 = (n0+n1+n2+n3+n4+n5)/4;
    mcvt_k<<<dim3((tot4+255)/256), 256, 0, stream>>>(
        ainW, attn_in_w, n0, aoutW, attn_out_w, n1, f1W, ff1_w, n2,
        f2W, ff2_w, n3, dcatW, dec_cat_w, n4, dcooW, dec_coo_w, n5);
  }
  wcomb_k<<<dim3(2048, 7, SIDES), 256, 0, stream>>>(wcomb, Wf, Wiou, Uiou);
  bcomb_k<<<dim3(8, 1, SIDES), 256, 0, stream>>>(bcomb, biou);
  padcvt_k<<<dim3(5000, 2, SIDES), 256, 0, stream>>>(c2pB, cat2poi_w, 5000, 300, 320);
  padcvt_k<<<dim3(5000, 1, SIDES), 256, 0, stream>>>(o2pB, coo2poi_w, 5000, 50, 64);
  tpcvt_k<<<dim3(512, 1, SIDES), 320, 0, stream>>>(dctT, dec_cat_w, 300, 320);
  tpcvt_k<<<dim3(512, 1, SIDES), 64, 0, stream>>>(dcoT, dec_coo_w, 50, 64);
  weffinit_k<<<dim3(2500, 1, SIDES), 256, 0, stream>>>(weffB, dec_poi_w, mtl);
  beff_k<<<dim3(20, 1, SIDES), 256, 0, stream>>>(beff, dec_poi_b, dec_cat_b,
       cat2poi_w, cat2poi_b, dec_coo_b, coo2poi_w, coo2poi_b, mtl);

  // ---- embeddings ----
  embed_k<<<dim3(NN, 1, SIDES), 256, 0, stream>>>(user_ids, feat_ids, time_ids, mask,
                                                  user_emb, fuse_emb, time_pe, Xb);

  // ---- leaves: iou0 = x @ Wiou^T (rows of wcomb 512..2047, K=256), no bias ----
  GEMM(0, true, Xb, 256L, X_S, Xb, 256L, X_S, 256, 729, 364,
       wcomb + (long)512*1792, 1792L, (long)2048*1792,
       (const float*)nullptr, 0L, QKV, 1536L, QKV_S, 5832, 1536, 256);
  leaf_k<<<dim3(5832, 1, SIDES), 256, 0, stream>>>(QKV, c0, Hb, Cb);

  const int p3[7]   = {1,3,9,27,81,243,729};
  const int offs[7] = {0,1,4,13,40,121,364};

  // ---- internal levels ----
  for (int l = 5; l >= 0; l--){
    int n = p3[l], st = offs[l], cs = offs[l+1];
    int P = NTREE*n, T = 3*P;
    for (int L = 0; L < LAYERS; L++){
      const ushort* zin = (L == 0) ? Hb : Zb;
      long zld = 512, zs = (L == 0) ? H_S : Z_S;
      int mN = (L == 0) ? 3*n : 0, mO = (L == 0) ? cs : 0;
      GEMM(0, true, zin, zld, zs, zin, zld, zs, 512, mN, mO,
           ainW + (long)L*1536*512, 512L, (long)2*1536*512,
           attn_in_b + (long)L*1536, (long)LAYERS*1536, QKV, 1536L, QKV_S, T, 1536, 512);
      attn_k<<<dim3(P, 2, SIDES), 256, 0, stream>>>(QKV, TMP);
      GEMM(0, true, TMP, 512L, Z_S, TMP, 512L, Z_S, 512, 0, 0,
           aoutW + (long)L*512*512, 512L, (long)2*512*512,
           attn_out_b + (long)L*512, (long)LAYERS*512, QKV, 512L, QKV_S, T, 512, 512);
      add_ln_k<<<dim3(T, 1, SIDES), 256, 0, stream>>>(Zb, Z_S, zin, zs, mN, mO,
           QKV, QKV_S, ln1_w + (long)L*512, ln1_b + (long)L*512, (long)LAYERS*512);
      GEMM(1, true, Zb, 512L, Z_S, Zb, 512L, Z_S, 512, 0, 0,
           f1W + (long)L*512*512, 512L, (long)2*512*512,
           ff1_b + (long)L*512, (long)LAYERS*512, TMP, 512L, Z_S, T, 512, 512);
      GEMM(0, true, TMP, 512L, Z_S, TMP, 512L, Z_S, 512, 0, 0,
           f2W + (long)L*512*512, 512L, (long)2*512*512,
           ff2_b + (long)L*512, (long)LAYERS*512, QKV, 512L, QKV_S, T, 512, 512);
      add_ln_k<<<dim3(T, 1, SIDES), 256, 0, stream>>>(Zb, Z_S, Zb, Z_S, 0, 0,
           QKV, QKV_S, ln2_w + (long)L*512, ln2_b + (long)L*512, (long)LAYERS*512);
    }
    // [wx | iou] = [x | z] @ [Wf|0 ; Wiou|Uiou]^T + [0|biou]
    GEMM(0, true, Xb, 256L, X_S, Zb, 1536L, Z_S, 256, n, st,
         wcomb, 1792L, (long)2048*1792, bcomb, 2048L, WXI, 2048L, WXI_S, P, 2048, 1792);
    combine_k<<<dim3(P, 1, SIDES), 256, 0, stream>>>(WXI, Zb, bf, Cb, Hb, Cb, n, st, cs);
  }

  // ---- cat/coo decoders (per-side W stride = NCAT*512 / NCOO*512!) ----
  GEMM(0, false, Hb, 512L, H_S, Hb, 512L, H_S, 512, 0, 0,
       dcatW, 512L, (long)NCAT*512, dec_cat_b, (long)NCAT,
       out + CAT_OFF, (long)NCAT, OUT_S, NN, NCAT, 512);
  GEMM(0, false, Hb, 512L, H_S, Hb, 512L, H_S, 512, 0, 0,
       dcooW, 512L, (long)NCOO*512, dec_coo_b, (long)NCOO,
       out + COO_OFF, (long)NCOO, OUT_S, NN, NCOO, 512);

  // ---- Weff += a1*cat2poi@dec_cat^T, += a2*coo2poi@dec_coo^T (bf16 RMW) ----
  GEMM4(true, c2pB, 320L, (long)5000*320, dctT, 320L, (long)512*320,
        weffB, 512L, WEFF_S, 5000, 512, 320, 1);
  GEMM4(true, o2pB, 64L, (long)5000*64, dcoT, 64L, (long)512*64,
        weffB, 512L, WEFF_S, 5000, 512, 64, 2);

  // ---- fused poi decoder ----
  GEMM(0, false, Hb, 512L, H_S, Hb, 512L, H_S, 512, 0, 0,
       weffB, 512L, WEFF_S, beff, (long)NPOI,
       out, (long)NPOI, OUT_S, NN, NPOI, 512);
}

// Round 8
// 1559.863 us; speedup vs baseline: 7.0505x; 1.0585x over previous
//
#include <hip/hip_runtime.h>
#include <math.h>

#define SIDES 2
#define LAYERS 2
#define NTREE 8
#define NPT 1093
#define NN (NTREE*NPT)        // 8744
#define EE 256
#define HH 512
#define NUSERS 2000
#define NPOI 5000
#define NCAT 300
#define NCOO 50
#define FUSEN 5350
#define TMAXN 600
#define TOKMAX 5832           // 8*729
#define PARMAX 1944           // 8*243

constexpr long OUT_S   = 46780400L;   // per-side output block (floats)
constexpr long CAT_OFF = 43720000L;
constexpr long COO_OFF = 46343200L;

// element strides per side
constexpr long H_S    = (long)NN*HH;        // 4,476,928
constexpr long X_S    = (long)NN*EE;        // 2,238,464
constexpr long Z_S    = (long)TOKMAX*HH;    // 2,985,984
constexpr long QKV_S  = (long)TOKMAX*3*HH;  // 8,957,952
constexpr long WXI_S  = (long)PARMAX*2048;  // 3,981,312
constexpr long WEFF_S = (long)NPOI*HH;      // 2,560,000

typedef __attribute__((ext_vector_type(8))) short  bf16x8;
typedef __attribute__((ext_vector_type(8))) ushort u16x8;
typedef __attribute__((ext_vector_type(4))) ushort u16x4;
typedef __attribute__((ext_vector_type(4))) float  f32x4;

__device__ __forceinline__ float sigm(float x){ return 1.f/(1.f+expf(-x)); }
__device__ __forceinline__ ushort f2b(float f){
  union { float f; unsigned u; } v; v.f = f;
  return (ushort)((v.u + 0x7fffu + ((v.u >> 16) & 1u)) >> 16);
}
__device__ __forceinline__ float b2f(ushort u){
  union { unsigned u; float f; } v; v.u = (unsigned)u << 16; return v.f;
}

// ================= merged prep kernel (preconvert + embed) =================
// block ranges: [emb | mcvt | wcomb | bcomb | poi-rows | tp-rows | weff | beff]
constexpr int PB_EMB  = 2*NN;      // 17488
constexpr int PB_MCVT = 6494;      // (3145728+3*1048576+307200+51200)/4/256
constexpr int PB_WCOMB= 2*2048;    // 4096
constexpr int PB_BCOMB= 16;
constexpr int PB_POI  = 2*5000;    // 10000
constexpr int PB_TP   = 2*512;     // 1024
constexpr int PB_WEI  = 2*2500;    // 5000
constexpr int PB_BEF  = 40;
constexpr int PB_TOT  = PB_EMB+PB_MCVT+PB_WCOMB+PB_BCOMB+PB_POI+PB_TP+PB_WEI+PB_BEF;

__global__ void __launch_bounds__(256) prep_k(
    const int* __restrict__ uid, const int* __restrict__ fid,
    const int* __restrict__ tids, const int* __restrict__ mask,
    const float* __restrict__ uemb, const float* __restrict__ femb,
    const float* __restrict__ tpe, ushort* __restrict__ X,
    ushort* ainW, const float* attn_in_w, ushort* aoutW, const float* attn_out_w,
    ushort* f1W, const float* ff1_w, ushort* f2W, const float* ff2_w,
    ushort* dcatW, const float* dec_cat_w, ushort* dcooW, const float* dec_coo_w,
    ushort* wcomb, const float* Wf, const float* Wiou, const float* Uiou,
    float* bcomb, const float* biou,
    ushort* c2pB, const float* cat2poi_w, ushort* o2pB, const float* coo2poi_w,
    ushort* dctT, ushort* dcoT,
    ushort* weffB, const float* dec_poi_w, const float* mtl,
    float* beff, const float* dec_poi_b, const float* dec_cat_b,
    const float* cat2poi_b, const float* dec_coo_b, const float* coo2poi_b){
  int b = blockIdx.x;
  int tid = threadIdx.x;
  if (b < PB_EMB){
    int s = b / NN; long i = b - s*NN; int d = tid;
    int m = mask[(long)s*NN + i];
    int u = uid[(long)s*NN + i]*m, f = fid[(long)s*NN + i]*m, t = tids[(long)s*NN + i]*m;
    float e = (d < 128) ? uemb[((long)s*NUSERS + u)*128 + d]
                        : femb[((long)s*FUSEN + f)*128 + (d-128)];
    e += 0.5f * tpe[((long)s*TMAXN + t)*256 + d];
    X[(long)s*X_S + i*EE + d] = f2b(e * (float)m);
    return;
  }
  b -= PB_EMB;
  if (b < PB_MCVT){
    const long n0 = 3145728, n1 = 1048576, n2 = 1048576, n3 = 1048576,
               n4 = 307200, n5 = 51200;
    long i = ((long)b*256 + tid)*4;
    ushort* d; const float* s; long off;
    if      (i < n0){ d=ainW;  s=attn_in_w;  off=i; }
    else if ((i-=n0) < n1){ d=aoutW; s=attn_out_w; off=i; }
    else if ((i-=n1) < n2){ d=f1W;  s=ff1_w;  off=i; }
    else if ((i-=n2) < n3){ d=f2W;  s=ff2_w;  off=i; }
    else if ((i-=n3) < n4){ d=dcatW; s=dec_cat_w; off=i; }
    else if ((i-=n4) < n5){ d=dcooW; s=dec_coo_w; off=i; }
    else return;
    f32x4 v = *(const f32x4*)(s + off);
    *(u16x4*)(d + off) = (u16x4){f2b(v[0]), f2b(v[1]), f2b(v[2]), f2b(v[3])};
    return;
  }
  b -= PB_MCVT;
  if (b < PB_WCOMB){
    int s = b >> 11; int row = b & 2047;
    ushort* dst = wcomb + (long)s*2048*1792 + (long)row*1792;
    for (int col = tid; col < 1792; col += 256){
      float v;
      if (row < 512) v = (col < 256) ? Wf[((long)s*512 + row)*256 + col] : 0.f;
      else {
        int r = row - 512;
        v = (col < 256) ? Wiou[((long)s*1536 + r)*256 + col]
                        : Uiou[((long)s*1536 + r)*1536 + (col-256)];
      }
      dst[col] = f2b(v);
    }
    return;
  }
  b -= PB_WCOMB;
  if (b < PB_BCOMB){
    int s = b >> 3; int c = (b & 7)*256 + tid;
    bcomb[(long)s*2048 + c] = (c < 512) ? 0.f : biou[(long)s*1536 + (c-512)];
    return;
  }
  b -= PB_BCOMB;
  if (b < PB_POI){
    int s = b / 5000; int r = b - s*5000;
    for (int c = tid; c < 320; c += 256){
      float v = (c < 300) ? cat2poi_w[((long)s*5000 + r)*300 + c] : 0.f;
      c2pB[((long)s*5000 + r)*320 + c] = f2b(v);
    }
    if (tid < 64){
      float v = (tid < 50) ? coo2poi_w[((long)s*5000 + r)*50 + tid] : 0.f;
      o2pB[((long)s*5000 + r)*64 + tid] = f2b(v);
    }
    return;
  }
  b -= PB_POI;
  if (b < PB_TP){
    int s = b >> 9; int h = b & 511;
    for (int c = tid; c < 320; c += 256){
      float v = (c < 300) ? dec_cat_w[((long)s*300 + c)*512 + h] : 0.f;
      dctT[((long)s*512 + h)*320 + c] = f2b(v);
    }
    if (tid < 64){
      float v = (tid < 50) ? dec_coo_w[((long)s*50 + tid)*512 + h] : 0.f;
      dcoT[((long)s*512 + h)*64 + tid] = f2b(v);
    }
    return;
  }
  b -= PB_TP;
  if (b < PB_WEI){
    int s = b / 2500; int blk = b - s*2500;
    long i = ((long)blk*256 + tid)*4;
    float a0 = 0.5f*expf(-mtl[(long)s*3]);
    f32x4 v = *(const f32x4*)(dec_poi_w + (long)s*WEFF_S + i);
    *(u16x4*)(weffB + (long)s*WEFF_S + i) =
        (u16x4){f2b(a0*v[0]), f2b(a0*v[1]), f2b(a0*v[2]), f2b(a0*v[3])};
    return;
  }
  b -= PB_WEI;
  {
    int s = b / 20; int n = (b - s*20)*256 + tid;
    if (n >= NPOI) return;
    const float* mt = mtl + (long)s*3;
    float a0 = 0.5f*expf(-mt[0]), a1 = 0.5f*expf(-mt[1]), a2 = 0.5f*expf(-mt[2]);
    float acc1 = 0.f, acc2 = 0.f;
    for (int c = 0; c < NCAT; c++)
      acc1 += dec_cat_b[(long)s*NCAT + c] * cat2poi_w[((long)s*NPOI + n)*NCAT + c];
    for (int c = 0; c < NCOO; c++)
      acc2 += dec_coo_b[(long)s*NCOO + c] * coo2poi_w[((long)s*NPOI + n)*NCOO + c];
    beff[(long)s*NPOI + n] = a0*dec_poi_b[(long)s*NPOI + n]
        + a1*(acc1 + cat2poi_b[(long)s*NPOI + n]) + a2*(acc2 + coo2poi_b[(long)s*NPOI + n])
        + mt[0] + mt[1] + mt[2];
  }
}

// ================= bf16 MFMA GEMM (unchanged from R7) =================
template<int MODE, bool OBF>
__global__ void __launch_bounds__(256)
mgemm_k(const ushort* __restrict__ A1, long lda1, long sA1,
        const ushort* __restrict__ A2, long lda2, long sA2,
        int kSplit, int mapN, int mapOff,
        const ushort* __restrict__ Wt, long ldw, long sW,
        const float* __restrict__ bias, long sB,
        void* __restrict__ Cv, long ldc, long sC,
        int M, int Nc, int K, int nbx,
        const float* __restrict__ mtl, int mtlIdx){
  int s = blockIdx.z;
  A1 += (long)s*sA1; A2 += (long)s*sA2; Wt += (long)s*sW;
  if (bias) bias += (long)s*sB;

  int flat = blockIdx.x, nwg = gridDim.x;
  int xcd = flat & 7, q = nwg >> 3, r8 = nwg & 7;
  int nf = (xcd < r8 ? xcd*(q+1) : r8*(q+1) + (xcd - r8)*q) + (flat >> 3);
  int bx = nf % nbx, by = nf / nbx;
  int m0 = by*128, n0 = bx*128;

  __shared__ ushort As[128*64];
  __shared__ ushort Ws[128*64];

  int tid = threadIdx.x;
  int lane = tid & 63, wave = tid >> 6;
  int wr = wave >> 1, wc = wave & 1;
  int fr = lane & 15, kc = lane >> 4;

  int baseRow = tid >> 3;
  int c16 = tid & 7;
  int col8 = c16*8;
  int swz = (baseRow & 7) << 4;

  long gA1[4], gA2[4], gW[4];
  int wbyte[4];
  #pragma unroll
  for (int c = 0; c < 4; c++){
    int row = baseRow + c*32;
    int ra = m0 + row; if (ra > M-1) ra = M-1;
    gA2[c] = ra;
    if (mapN > 0){ int tr = ra / mapN; gA1[c] = (long)(tr*NPT + mapOff + (ra - tr*mapN)); }
    else gA1[c] = ra;
    int rw = n0 + row; if (rw > Nc-1) rw = Nc-1;
    gW[c] = rw;
    wbyte[c] = row*128 + ((c16*16) ^ swz);
  }

  u16x8 rA[4], rW[4];
  {
    bool u1 = (0 < kSplit);
    const ushort* asrc = u1 ? A1 : A2;
    long ld = u1 ? lda1 : lda2;
    const long* g = u1 ? gA1 : gA2;
    #pragma unroll
    for (int c = 0; c < 4; c++){
      rA[c] = *(const u16x8*)(asrc + g[c]*ld + col8);
      rW[c] = *(const u16x8*)(Wt + gW[c]*ldw + col8);
    }
  }

  f32x4 acc[4][4];
  #pragma unroll
  for (int i = 0; i < 4; i++)
    #pragma unroll
    for (int j = 0; j < 4; j++) acc[i][j] = (f32x4){0.f,0.f,0.f,0.f};

  for (int k0 = 0; k0 < K; k0 += 64){
    #pragma unroll
    for (int c = 0; c < 4; c++){
      *(u16x8*)((char*)As + wbyte[c]) = rA[c];
      *(u16x8*)((char*)Ws + wbyte[c]) = rW[c];
    }
    __syncthreads();
    int kn = k0 + 64;
    if (kn < K){
      bool u1 = (kn < kSplit);
      const ushort* asrc = u1 ? A1 : A2;
      long ld = u1 ? lda1 : lda2;
      const long* g = u1 ? gA1 : gA2;
      long colb = u1 ? (long)kn : (long)(kn - kSplit);
      #pragma unroll
      for (int c = 0; c < 4; c++){
        rA[c] = *(const u16x8*)(asrc + g[c]*ld + colb + col8);
        rW[c] = *(const u16x8*)(Wt + gW[c]*ldw + kn + col8);
      }
    }
    #pragma unroll
    for (int h = 0; h < 2; h++){
      bf16x8 af[4], bw[4];
      #pragma unroll
      for (int i = 0; i < 4; i++){
        int row = wr*64 + i*16 + fr;
        int byo = row*128 + ((h*64 + kc*16) ^ ((row & 7) << 4));
        af[i] = *(const bf16x8*)((const char*)As + byo);
      }
      #pragma unroll
      for (int j = 0; j < 4; j++){
        int row = wc*64 + j*16 + fr;
        int byo = row*128 + ((h*64 + kc*16) ^ ((row & 7) << 4));
        bw[j] = *(const bf16x8*)((const char*)Ws + byo);
      }
      #pragma unroll
      for (int i = 0; i < 4; i++)
        #pragma unroll
        for (int j = 0; j < 4; j++)
          acc[i][j] = __builtin_amdgcn_mfma_f32_16x16x32_bf16(bw[j], af[i], acc[i][j], 0, 0, 0);
    }
    __syncthreads();
  }

  float alpha = 1.f;
  if (MODE == 4) alpha = 0.5f*expf(-mtl[(long)s*3 + mtlIdx]);
  int ccol = lane & 15, cr4 = (lane >> 4)*4;
  bool vecN = ((Nc & 3) == 0);
  float* Cf = (float*)Cv + (long)s*sC;
  ushort* Cb = (ushort*)Cv + (long)s*sC;
  #pragma unroll
  for (int i = 0; i < 4; i++){
    int gm = m0 + wr*64 + i*16 + ccol;
    if (gm >= M) continue;
    long rowoff = (long)gm*ldc;
    #pragma unroll
    for (int j = 0; j < 4; j++){
      int gn0 = n0 + wc*64 + j*16 + cr4;
      if (gn0 >= Nc) continue;
      f32x4 v = acc[i][j];
      if (MODE != 4 && bias){ f32x4 bv = *(const f32x4*)&bias[gn0]; v += bv; }
      if (MODE == 1){ v = (f32x4){fmaxf(v[0],0.f),fmaxf(v[1],0.f),fmaxf(v[2],0.f),fmaxf(v[3],0.f)}; }
      if (OBF){
        u16x4* cp = (u16x4*)&Cb[rowoff + gn0];
        if (MODE == 4){
          u16x4 o = *cp;
          *cp = (u16x4){f2b(b2f(o[0]) + alpha*v[0]), f2b(b2f(o[1]) + alpha*v[1]),
                        f2b(b2f(o[2]) + alpha*v[2]), f2b(b2f(o[3]) + alpha*v[3])};
        } else {
          *cp = (u16x4){f2b(v[0]), f2b(v[1]), f2b(v[2]), f2b(v[3])};
        }
      } else {
        if (vecN){
          f32x4* cp = (f32x4*)&Cf[rowoff + gn0];
          if (MODE == 4){ f32x4 o = *cp; *cp = o + alpha*v; }
          else *cp = v;
        } else {
          #pragma unroll
          for (int r = 0; r < 4; r++){
            int gn = gn0 + r; if (gn >= Nc) continue;
            if (MODE == 4) Cf[rowoff + gn] += alpha*v[r];
            else Cf[rowoff + gn] = v[r];
          }
        }
      }
    }
  }
}

// ================= 3x3 attention: one wave per (seq, head), barrier-free ======
// grid: (P/2, 1, SIDES), 256 threads = 4 waves = 2 seqs x 2 heads
__global__ void __launch_bounds__(256) attn_k(const ushort* __restrict__ qkv,
                                              ushort* __restrict__ o){
  int s = blockIdx.z;
  int w = threadIdx.x >> 6, lane = threadIdx.x & 63;
  int seq = blockIdx.x*2 + (w >> 1);
  int h = w & 1;
  const ushort* base = qkv + (long)s*QKV_S + (long)seq*3*1536 + h*256 + lane*4;
  float q[3][4], k[3][4], v[3][4];
  #pragma unroll
  for (int i = 0; i < 3; i++){
    u16x4 tq = *(const u16x4*)(base + (long)i*1536);
    u16x4 tk = *(const u16x4*)(base + (long)i*1536 + 512);
    u16x4 tv = *(const u16x4*)(base + (long)i*1536 + 1024);
    #pragma unroll
    for (int e = 0; e < 4; e++){ q[i][e]=b2f(tq[e]); k[i][e]=b2f(tk[e]); v[i][e]=b2f(tv[e]); }
  }
  float p[9];
  #pragma unroll
  for (int i = 0; i < 3; i++)
    #pragma unroll
    for (int j = 0; j < 3; j++){
      float acc = 0.f;
      #pragma unroll
      for (int e = 0; e < 4; e++) acc += q[i][e]*k[j][e];
      p[i*3+j] = acc;
    }
  #pragma unroll
  for (int m = 1; m < 64; m <<= 1)
    #pragma unroll
    for (int t = 0; t < 9; t++) p[t] += __shfl_xor(p[t], m);
  float att[9];
  #pragma unroll
  for (int i = 0; i < 3; i++){
    float a = p[i*3]*0.0625f, bb = p[i*3+1]*0.0625f, c = p[i*3+2]*0.0625f;
    float mx = fmaxf(a, fmaxf(bb, c));
    a = expf(a-mx); bb = expf(bb-mx); c = expf(c-mx);
    float inv = 1.f/(a+bb+c);
    att[i*3] = a*inv; att[i*3+1] = bb*inv; att[i*3+2] = c*inv;
  }
  ushort* ob = o + (long)s*Z_S + (long)seq*1536 + h*256 + lane*4;
  #pragma unroll
  for (int i = 0; i < 3; i++){
    u16x4 r;
    #pragma unroll
    for (int e = 0; e < 4; e++)
      r[e] = f2b(att[i*3]*v[0][e] + att[i*3+1]*v[1][e] + att[i*3+2]*v[2][e]);
    *(u16x4*)(ob + (long)i*512) = r;
  }
}

// ================= z = LN(res + t): one wave per row, barrier-free ============
// grid: (T/4, 1, SIDES), 256 threads = 4 waves = 4 rows
__global__ void __launch_bounds__(256) add_ln_k(ushort* __restrict__ zout, long sZ,
                         const ushort* __restrict__ res, long sR, int mapN, int mapOff,
                         const ushort* __restrict__ tb, long sT,
                         const float* __restrict__ w, const float* __restrict__ b,
                         long wstr){
  int s = blockIdx.z;
  int wv = threadIdx.x >> 6, lane = threadIdx.x & 63;
  int r = blockIdx.x*4 + wv;
  int g = r;
  if (mapN > 0){ int tr = r / mapN; g = tr*NPT + mapOff + (r - tr*mapN); }
  int d0 = lane*8;
  u16x8 rr = *(const u16x8*)(res + (long)s*sR + (long)g*HH + d0);
  u16x8 tt = *(const u16x8*)(tb  + (long)s*sT + (long)r*HH + d0);
  float x[8];
  float sum = 0.f;
  #pragma unroll
  for (int e = 0; e < 8; e++){ x[e] = b2f(rr[e]) + b2f(tt[e]); sum += x[e]; }
  #pragma unroll
  for (int m = 1; m < 64; m <<= 1) sum += __shfl_xor(sum, m);
  float mean = sum * (1.f/512.f);
  float vs = 0.f;
  #pragma unroll
  for (int e = 0; e < 8; e++){ float d = x[e]-mean; vs += d*d; }
  #pragma unroll
  for (int m = 1; m < 64; m <<= 1) vs += __shfl_xor(vs, m);
  float inv = 1.f/sqrtf(vs*(1.f/512.f) + 1e-5f);
  const float* wr_ = w + (long)s*wstr + d0;
  const float* br_ = b + (long)s*wstr + d0;
  f32x4 w0 = *(const f32x4*)wr_, w1 = *(const f32x4*)(wr_+4);
  f32x4 b0 = *(const f32x4*)br_, b1 = *(const f32x4*)(br_+4);
  u16x8 ov;
  #pragma unroll
  for (int e = 0; e < 4; e++){
    ov[e]   = f2b((x[e]-mean)*inv*w0[e] + b0[e]);
    ov[e+4] = f2b((x[e+4]-mean)*inv*w1[e] + b1[e]);
  }
  *(u16x8*)(zout + (long)s*sZ + (long)r*HH + d0) = ov;
}

// ================= leaf LSTM cell =================
__global__ void leaf_k(const ushort* __restrict__ iou, const float* __restrict__ c0,
                       ushort* __restrict__ hbuf, float* __restrict__ cbuf){
  int s = blockIdx.z, p = blockIdx.x;
  int tree = p / 729, j = p - tree*729;
  long row = (long)(tree*NPT + 364 + j)*HH;
  const ushort* iour = iou + (long)s*QKV_S + (long)p*1536;
  const float* c0r = c0 + (long)s*H_S + row;
  for (int d = threadIdx.x; d < HH; d += 256){
    float cn = sigm(b2f(iour[d])) * tanhf(b2f(iour[1024 + d])) + c0r[d];
    float hn = sigm(b2f(iour[512 + d])) * tanhf(cn);
    hbuf[(long)s*H_S + row + d] = f2b(hn);
    cbuf[(long)s*H_S + row + d] = cn;
  }
}

// ================= internal-node combine =================
__global__ void combine_k(const ushort* __restrict__ wxiou, const ushort* __restrict__ z,
                          const float* __restrict__ bfv, const float* __restrict__ cbuf,
                          ushort* __restrict__ hbuf, float* __restrict__ cout,
                          int n, int st, int cs){
  int s = blockIdx.z, p = blockIdx.x;
  int tree = p / n, j = p - tree*n;
  const ushort* wr_ = wxiou + (long)s*WXI_S + (long)p*2048;
  const ushort* zr  = z + (long)s*Z_S + (long)p*1536;
  const float* bfr  = bfv + (long)s*HH;
  const float* cch  = cbuf + (long)s*H_S + (long)(tree*NPT + cs + 3*j)*HH;
  long orow = (long)s*H_S + (long)(tree*NPT + st + j)*HH;
  for (int d = threadIdx.x; d < HH; d += 256){
    float wv = b2f(wr_[d]) + bfr[d];
    float cpre = 0.f;
    #pragma unroll
    for (int ch = 0; ch < 3; ch++){
      float fg = sigm(wv + b2f(zr[ch*512 + d]));
      cpre += fg * cch[ch*512 + d];
    }
    float iv = b2f(wr_[512 + d]), ov = b2f(wr_[1024 + d]), uv = b2f(wr_[1536 + d]);
    float cn = sigm(iv)*tanhf(uv) + cpre;
    float hn = sigm(ov)*tanhf(cn);
    hbuf[orow + d] = f2b(hn);
    cout[orow + d] = cn;
  }
}

// launch helpers
#define GEMM(MODE, OBF, A1, LDA1, SA1, A2, LDA2, SA2, KSPL, MAPN, MAPOFF, WT, LDW, SW, \
             BI, SB, CC, LDC, SC, M, NC, K)                                            \
  do { int nbx_ = ((NC)+127)/128, nby_ = ((M)+127)/128;                                \
    mgemm_k<MODE, OBF><<<dim3(nbx_*nby_, 1, SIDES), 256, 0, stream>>>(                 \
      A1, LDA1, SA1, A2, LDA2, SA2, KSPL, MAPN, MAPOFF, WT, LDW, SW, BI, SB,           \
      CC, LDC, SC, M, NC, K, nbx_, mtl, 0); } while(0)
#define GEMM4(OBF, A1, LDA1, SA1, WT, LDW, SW, CC, LDC, SC, M, NC, K, IDX)             \
  do { int nbx_ = ((NC)+127)/128, nby_ = ((M)+127)/128;                                \
    mgemm_k<4, OBF><<<dim3(nbx_*nby_, 1, SIDES), 256, 0, stream>>>(                    \
      A1, LDA1, SA1, A1, LDA1, SA1, K, 0, 0, WT, LDW, SW, (const float*)nullptr, 0L,   \
      CC, LDC, SC, M, NC, K, nbx_, mtl, IDX); } while(0)

extern "C" void kernel_launch(void* const* d_in, const int* in_sizes, int n_in,
                              void* d_out, int out_size, void* d_ws, size_t ws_size,
                              hipStream_t stream){
  (void)in_sizes; (void)n_in; (void)out_size; (void)ws_size;
  const int*   user_ids  = (const int*)d_in[0];
  const int*   feat_ids  = (const int*)d_in[1];
  const int*   time_ids  = (const int*)d_in[2];
  const int*   mask      = (const int*)d_in[3];
  const float* user_emb  = (const float*)d_in[6];
  const float* fuse_emb  = (const float*)d_in[7];
  const float* time_pe   = (const float*)d_in[8];
  const float* Wf        = (const float*)d_in[9];
  const float* bf        = (const float*)d_in[10];
  const float* Wiou      = (const float*)d_in[11];
  const float* Uiou      = (const float*)d_in[12];
  const float* biou      = (const float*)d_in[13];
  const float* attn_in_w = (const float*)d_in[14];
  const float* attn_in_b = (const float*)d_in[15];
  const float* attn_out_w= (const float*)d_in[16];
  const float* attn_out_b= (const float*)d_in[17];
  const float* ff1_w     = (const float*)d_in[18];
  const float* ff1_b     = (const float*)d_in[19];
  const float* ff2_w     = (const float*)d_in[20];
  const float* ff2_b     = (const float*)d_in[21];
  const float* ln1_w     = (const float*)d_in[22];
  const float* ln1_b     = (const float*)d_in[23];
  const float* ln2_w     = (const float*)d_in[24];
  const float* ln2_b     = (const float*)d_in[25];
  const float* dec_poi_w = (const float*)d_in[26];
  const float* dec_poi_b = (const float*)d_in[27];
  const float* dec_cat_w = (const float*)d_in[28];
  const float* dec_cat_b = (const float*)d_in[29];
  const float* dec_coo_w = (const float*)d_in[30];
  const float* dec_coo_b = (const float*)d_in[31];
  const float* cat2poi_w = (const float*)d_in[32];
  const float* cat2poi_b = (const float*)d_in[33];
  const float* coo2poi_w = (const float*)d_in[34];
  const float* coo2poi_b = (const float*)d_in[35];
  const float* mtl       = (const float*)d_in[36];
  const float* c0        = (const float*)d_in[37];

  float* out = (float*)d_out;

  // ---- ws layout (bf16 persistent: Hb, weights) ----
  ushort* wsu = (ushort*)d_ws;
  ushort* Hb    = wsu;                         // [2][NN*512]
  ushort* ainW  = Hb    + 2*H_S;               // [2][2][1536*512]
  ushort* aoutW = ainW  + (long)2*2*1536*512;  // [2][2][512*512]
  ushort* f1W   = aoutW + (long)2*2*512*512;
  ushort* f2W   = f1W   + (long)2*2*512*512;
  ushort* wcomb = f2W   + (long)2*2*512*512;   // [2][2048*1792]
  ushort* dcatW = wcomb + (long)2*2048*1792;   // [2][300*512]
  ushort* dcooW = dcatW + (long)2*300*512;     // [2][50*512]
  ushort* weffB = dcooW + (long)2*50*512;      // [2][5000*512]
  float*  bcomb = (float*)(weffB + (long)2*WEFF_S);  // [2][2048]
  float*  beff  = bcomb + 2*2048;              // [2][5000]

  // ---- out-scratch (side-1 poi region; dead before final GEMM writes it) ----
  float*  Cb   = out + OUT_S;                  // [2][NN*512] f32
  ushort* osu  = (ushort*)(Cb + 2*H_S);
  ushort* QKV  = osu;                          // [2][TOKMAX*1536]
  ushort* Zb   = QKV  + 2*QKV_S;               // [2][TOKMAX*512]
  ushort* TMP  = Zb   + 2*Z_S;
  ushort* WXI  = TMP  + 2*Z_S;                 // [2][PARMAX*2048]
  ushort* Xb   = WXI  + 2*WXI_S;               // [2][NN*256]
  ushort* c2pB = Xb   + 2*X_S;                 // [2][5000*320]
  ushort* o2pB = c2pB + (long)2*5000*320;      // [2][5000*64]
  ushort* dctT = o2pB + (long)2*5000*64;       // [2][512*320]
  ushort* dcoT = dctT + (long)2*512*320;       // [2][512*64]

  // ---- merged prep (preconvert + embed) ----
  prep_k<<<dim3(PB_TOT), 256, 0, stream>>>(
      user_ids, feat_ids, time_ids, mask, user_emb, fuse_emb, time_pe, Xb,
      ainW, attn_in_w, aoutW, attn_out_w, f1W, ff1_w, f2W, ff2_w,
      dcatW, dec_cat_w, dcooW, dec_coo_w,
      wcomb, Wf, Wiou, Uiou, bcomb, biou,
      c2pB, cat2poi_w, o2pB, coo2poi_w, dctT, dcoT,
      weffB, dec_poi_w, mtl,
      beff, dec_poi_b, dec_cat_b, cat2poi_b, dec_coo_b, coo2poi_b);

  // ---- leaves: iou0 = x @ Wiou^T (rows of wcomb 512..2047, K=256), no bias ----
  GEMM(0, true, Xb, 256L, X_S, Xb, 256L, X_S, 256, 729, 364,
       wcomb + (long)512*1792, 1792L, (long)2048*1792,
       (const float*)nullptr, 0L, QKV, 1536L, QKV_S, 5832, 1536, 256);
  leaf_k<<<dim3(5832, 1, SIDES), 256, 0, stream>>>(QKV, c0, Hb, Cb);

  const int p3[7]   = {1,3,9,27,81,243,729};
  const int offs[7] = {0,1,4,13,40,121,364};

  // ---- internal levels ----
  for (int l = 5; l >= 0; l--){
    int n = p3[l], st = offs[l], cs = offs[l+1];
    int P = NTREE*n, T = 3*P;
    for (int L = 0; L < LAYERS; L++){
      const ushort* zin = (L == 0) ? Hb : Zb;
      long zld = 512, zs = (L == 0) ? H_S : Z_S;
      int mN = (L == 0) ? 3*n : 0, mO = (L == 0) ? cs : 0;
      GEMM(0, true, zin, zld, zs, zin, zld, zs, 512, mN, mO,
           ainW + (long)L*1536*512, 512L, (long)2*1536*512,
           attn_in_b + (long)L*1536, (long)LAYERS*1536, QKV, 1536L, QKV_S, T, 1536, 512);
      attn_k<<<dim3(P/2, 1, SIDES), 256, 0, stream>>>(QKV, TMP);
      GEMM(0, true, TMP, 512L, Z_S, TMP, 512L, Z_S, 512, 0, 0,
           aoutW + (long)L*512*512, 512L, (long)2*512*512,
           attn_out_b + (long)L*512, (long)LAYERS*512, QKV, 512L, QKV_S, T, 512, 512);
      add_ln_k<<<dim3(T/4, 1, SIDES), 256, 0, stream>>>(Zb, Z_S, zin, zs, mN, mO,
           QKV, QKV_S, ln1_w + (long)L*512, ln1_b + (long)L*512, (long)LAYERS*512);
      GEMM(1, true, Zb, 512L, Z_S, Zb, 512L, Z_S, 512, 0, 0,
           f1W + (long)L*512*512, 512L, (long)2*512*512,
           ff1_b + (long)L*512, (long)LAYERS*512, TMP, 512L, Z_S, T, 512, 512);
      GEMM(0, true, TMP, 512L, Z_S, TMP, 512L, Z_S, 512, 0, 0,
           f2W + (long)L*512*512, 512L, (long)2*512*512,
           ff2_b + (long)L*512, (long)LAYERS*512, QKV, 512L, QKV_S, T, 512, 512);
      add_ln_k<<<dim3(T/4, 1, SIDES), 256, 0, stream>>>(Zb, Z_S, Zb, Z_S, 0, 0,
           QKV, QKV_S, ln2_w + (long)L*512, ln2_b + (long)L*512, (long)LAYERS*512);
    }
    // [wx | iou] = [x | z] @ [Wf|0 ; Wiou|Uiou]^T + [0|biou]
    GEMM(0, true, Xb, 256L, X_S, Zb, 1536L, Z_S, 256, n, st,
         wcomb, 1792L, (long)2048*1792, bcomb, 2048L, WXI, 2048L, WXI_S, P, 2048, 1792);
    combine_k<<<dim3(P, 1, SIDES), 256, 0, stream>>>(WXI, Zb, bf, Cb, Hb, Cb, n, st, cs);
  }

  // ---- cat/coo decoders (per-side W stride = NCAT*512 / NCOO*512) ----
  GEMM(0, false, Hb, 512L, H_S, Hb, 512L, H_S, 512, 0, 0,
       dcatW, 512L, (long)NCAT*512, dec_cat_b, (long)NCAT,
       out + CAT_OFF, (long)NCAT, OUT_S, NN, NCAT, 512);
  GEMM(0, false, Hb, 512L, H_S, Hb, 512L, H_S, 512, 0, 0,
       dcooW, 512L, (long)NCOO*512, dec_coo_b, (long)NCOO,
       out + COO_OFF, (long)NCOO, OUT_S, NN, NCOO, 512);

  // ---- Weff += a1*cat2poi@dec_cat^T, += a2*coo2poi@dec_coo^T (bf16 RMW) ----
  GEMM4(true, c2pB, 320L, (long)5000*320, dctT, 320L, (long)512*320,
        weffB, 512L, WEFF_S, 5000, 512, 320, 1);
  GEMM4(true, o2pB, 64L, (long)5000*64, dcoT, 64L, (long)512*64,
        weffB, 512L, WEFF_S, 5000, 512, 64, 2);

  // ---- fused poi decoder ----
  GEMM(0, false, Hb, 512L, H_S, Hb, 512L, H_S, 512, 0, 0,
       weffB, 512L, WEFF_S, beff, (long)NPOI,
       out, (long)NPOI, OUT_S, NN, NPOI, 512);
}